// Round 9
// baseline (1306.434 us; speedup 1.0000x reference)
//
#include <hip/hip_runtime.h>
#include <hip/hip_bf16.h>
#include <math.h>

#define D     128
#define NHEAD 4
#define DH    32
#define DFF   512
#define DIN   16
#define MAXDEG 64
#define TN    16

typedef __attribute__((ext_vector_type(8))) short bf16x8;
typedef __attribute__((ext_vector_type(4))) float f32x4;
typedef __hip_bfloat16 bf16;

// 1/sqrt(32) * log2(e): q pre-scaled so attn weight = exp2(q.k)
#define QSCALE_L2E 0.2550348838f

// LDS row pad: 132 bf16 = 66 dwords; 4-row (quad) stride = 264 ≡ 8 (mod 32)
// -> quads land on bank groups {0,8,16,24}: conflict-free C-layout writes.
#define AP 132

// ---------------- CSR build ----------------
__global__ void k_zero_int(int* p, int n) {
    int i = blockIdx.x * blockDim.x + threadIdx.x;
    if (i < n) p[i] = 0;
}

__global__ void k_fill(const int* __restrict__ recv, const int* __restrict__ senders,
                       int* __restrict__ deg, int* __restrict__ eid, int E) {
    int e = blockIdx.x * blockDim.x + threadIdx.x;
    if (e >= E) return;
    int r = recv[e];
    int pos = atomicAdd(&deg[r], 1);
    if (pos < MAXDEG) eid[r * MAXDEG + pos] = senders[e];
}

// ---------------- weight transpose + bf16 convert (one launch, 25 regions) ----
__global__ void k_wt(const float* __restrict__ wq, const float* __restrict__ wk,
                     const float* __restrict__ wv, const float* __restrict__ wo,
                     const float* __restrict__ w1, const float* __restrict__ w2,
                     const float* __restrict__ encw2,
                     bf16* __restrict__ wqkvT, bf16* __restrict__ woT,
                     bf16* __restrict__ w1T, bf16* __restrict__ w2T,
                     bf16* __restrict__ encw2T) {
    int r = blockIdx.y;
    const float* src; bf16* dst; int K, Nout;
    if (r < 12) {
        int l = r / 3, sel = r % 3;
        src = (sel == 0 ? wq : sel == 1 ? wk : wv) + (size_t)l * D * D;
        dst = wqkvT + (size_t)l * 3 * D * D + (size_t)sel * D * D;
        K = D; Nout = D;
    } else if (r < 16) {
        int l = r - 12;
        src = wo + (size_t)l * D * D; dst = woT + (size_t)l * D * D; K = D; Nout = D;
    } else if (r < 20) {
        int l = r - 16;
        src = w1 + (size_t)l * D * DFF; dst = w1T + (size_t)l * D * DFF; K = D; Nout = DFF;
    } else if (r < 24) {
        int l = r - 20;
        src = w2 + (size_t)l * DFF * D; dst = w2T + (size_t)l * DFF * D; K = DFF; Nout = D;
    } else {
        src = encw2; dst = encw2T; K = D; Nout = D;
    }
    int total = K * Nout;
    int i = blockIdx.x * blockDim.x + threadIdx.x;
    if (i >= total) return;
    int k = i / Nout, j = i % Nout;
    dst[(size_t)j * K + k] = __float2bfloat16(src[i]);
}

// ---------------- bf16 MFMA GEMM, BM=64 x BN=128, K=128 (single-shot) -------
// A: [N][128] bf16 staged in LDS once.  Bt: [Nout][128]; block reads rows
// [y*128, y*128+128) as MFMA fragments DIRECTLY FROM GLOBAL (L2-resident).
// 4 waves, wave w owns rows [w*16, w*16+16) x 128 cols.
// OPs:
//   0 QKV    : y=0 -> qb bf16 * QSCALE_L2E; y=1 -> k (kvb even); y=2 -> v (odd)
//   2 RES_LN : x += val; LN(x) -> outB          (wo + ln2)
//   5 BIAS_LN: x = val + bias; LN(x) -> outB    (encode + ln1 of layer 0)
#define BM 64

template<int OP>
__global__ __launch_bounds__(256) void k_gemm(
        const bf16* A, const bf16* __restrict__ Bt,
        const float* __restrict__ bias,
        const float* __restrict__ lns, const float* __restrict__ lnb,
        float* x, bf16* qb, bf16* outB, int N) {
    __shared__ alignas(16) bf16 Asm[BM][AP];
    int m0 = blockIdx.x * BM;
    int y = blockIdx.y;
    const bf16* Bt_ = Bt + (size_t)y * 128 * D;
    int t = threadIdx.x;
    int wave = t >> 6, lane = t & 63;
    int quad = lane >> 4, l16 = lane & 15;
    int wm = wave * 16;

    // stage A: 64 x 128 = 1024 x 16B, 4/thread
#pragma unroll
    for (int it = 0; it < 4; it++) {
        int ci = it * 256 + t;
        int rr = ci >> 4, cc = (ci & 15) * 8;
        int gr = m0 + rr;
        uint4 val = make_uint4(0u, 0u, 0u, 0u);
        if (gr < N) val = *(const uint4*)(A + (size_t)gr * D + cc);
        *(uint4*)&Asm[rr][cc] = val;
    }
    __syncthreads();

    f32x4 acc[8];
#pragma unroll
    for (int j = 0; j < 8; j++) acc[j] = (f32x4){0.f, 0.f, 0.f, 0.f};

#pragma unroll
    for (int ks = 0; ks < 128; ks += 32) {
        bf16x8 af = *(const bf16x8*)&Asm[wm + l16][ks + quad * 8];
#pragma unroll
        for (int j = 0; j < 8; j++) {
            bf16x8 bfr = *(const bf16x8*)(Bt_ + (size_t)(j * 16 + l16) * D + ks + quad * 8);
            acc[j] = __builtin_amdgcn_mfma_f32_16x16x32_bf16(af, bfr, acc[j], 0, 0, 0);
        }
    }

    // ---- epilogue: C[row = quad*4+reg][col = lane&15] per 16x16 tile ----
    int rowb = m0 + wm + quad * 4;
    if (OP == 0) {             // QKV split
#pragma unroll
        for (int j = 0; j < 8; j++) {
            int col = j * 16 + l16;
#pragma unroll
            for (int r = 0; r < 4; r++) {
                int gr = rowb + r;
                if (gr >= N) continue;
                float val = acc[j][r];
                if (y == 0) qb[(size_t)gr * D + col] = __float2bfloat16(val * QSCALE_L2E);
                else outB[((size_t)gr * D + col) * 2 + (y - 1)] = __float2bfloat16(val);
            }
        }
        return;
    }
    // ---- full-row ops: residual/bias combine + LN ----
    {
        float bv[8];
        if (OP == 5) {
#pragma unroll
            for (int j = 0; j < 8; j++) bv[j] = bias[j * 16 + l16];
        }
#pragma unroll
        for (int j = 0; j < 8; j++) {
            int col = j * 16 + l16;
#pragma unroll
            for (int r = 0; r < 4; r++) {
                int gr = rowb + r;
                if (gr >= N) continue;
                float val = acc[j][r];
                if (OP == 5) val += bv[j];
                if (OP == 2) val += x[(size_t)gr * D + col];
                acc[j][r] = val;
            }
        }
        float lsv[8], lbv[8];
#pragma unroll
        for (int j = 0; j < 8; j++) {
            lsv[j] = lns[j * 16 + l16];
            lbv[j] = lnb[j * 16 + l16];
        }
#pragma unroll
        for (int r = 0; r < 4; r++) {
            float s1 = 0.f, s2 = 0.f;
#pragma unroll
            for (int j = 0; j < 8; j++) {
                float v = acc[j][r];
                s1 += v; s2 += v * v;
            }
            s1 += __shfl_xor(s1, 1, 64);  s2 += __shfl_xor(s2, 1, 64);
            s1 += __shfl_xor(s1, 2, 64);  s2 += __shfl_xor(s2, 2, 64);
            s1 += __shfl_xor(s1, 4, 64);  s2 += __shfl_xor(s2, 4, 64);
            s1 += __shfl_xor(s1, 8, 64);  s2 += __shfl_xor(s2, 8, 64);
            float mu = s1 * (1.f / 128.f);
            float var = s2 * (1.f / 128.f) - mu * mu;
            float rinv = rsqrtf(fmaxf(var, 0.f) + 1e-5f);
            int gr = rowb + r;
            if (gr >= N) continue;
#pragma unroll
            for (int j = 0; j < 8; j++) {
                int col = j * 16 + l16;
                float v = acc[j][r];
                x[(size_t)gr * D + col] = v;
                outB[(size_t)gr * D + col] =
                    __float2bfloat16((v - mu) * rinv * lsv[j] + lbv[j]);
            }
        }
    }
}

// ---------------- fused FFN: x += relu(hb@w1+b1)@w2 + b2 [; LN -> hb] --------
// Asm/Hsm in LDS (33.8 KB -> ~4 blocks/CU); W1/W2 fragments read directly
// from global (L2-resident, shared by all blocks). 2 barriers per chunk.
template<bool DOLN>
__global__ __launch_bounds__(256) void k_ffn(
        const bf16* hb, const bf16* __restrict__ w1T, const float* __restrict__ b1,
        const bf16* __restrict__ w2T, const float* __restrict__ b2,
        const float* __restrict__ lns, const float* __restrict__ lnb,
        float* x, bf16* outB, int N) {
    __shared__ alignas(16) bf16 Asm[64][AP];
    __shared__ alignas(16) bf16 Hsm[64][AP];
    int m0 = blockIdx.x * 64;
    int t = threadIdx.x;
    int wave = t >> 6, lane = t & 63;
    int quad = lane >> 4, l16 = lane & 15;
    int wm = wave * 16;

    // stage A: 64 x 128 = 1024 x 16B, 4/thread
#pragma unroll
    for (int it = 0; it < 4; it++) {
        int ci = it * 256 + t;
        int rr = ci >> 4, cc = (ci & 15) * 8;
        int gr = m0 + rr;
        uint4 val = make_uint4(0u, 0u, 0u, 0u);
        if (gr < N) val = *(const uint4*)(hb + (size_t)gr * D + cc);
        *(uint4*)&Asm[rr][cc] = val;
    }
    __syncthreads();

    f32x4 acc2[8];
#pragma unroll
    for (int j = 0; j < 8; j++) acc2[j] = (f32x4){0.f, 0.f, 0.f, 0.f};

    for (int c = 0; c < 4; c++) {
        // P = A @ W1c  (W1 fragments from global)
        f32x4 accP[8];
#pragma unroll
        for (int j = 0; j < 8; j++) accP[j] = (f32x4){0.f, 0.f, 0.f, 0.f};
#pragma unroll
        for (int ks = 0; ks < 128; ks += 32) {
            bf16x8 af = *(const bf16x8*)&Asm[wm + l16][ks + quad * 8];
#pragma unroll
            for (int j = 0; j < 8; j++) {
                bf16x8 bfr = *(const bf16x8*)(w1T +
                    (size_t)(c * 128 + j * 16 + l16) * D + ks + quad * 8);
                accP[j] = __builtin_amdgcn_mfma_f32_16x16x32_bf16(af, bfr, accP[j], 0, 0, 0);
            }
        }
        if (c > 0) __syncthreads();   // prev-chunk Hsm reads complete
        // Hsm = relu(P + b1), C-layout scalar writes (conflict-free at AP=132)
        {
            float bv[8];
#pragma unroll
            for (int j = 0; j < 8; j++) bv[j] = b1[c * 128 + j * 16 + l16];
            int rw = wm + quad * 4;
#pragma unroll
            for (int j = 0; j < 8; j++) {
                int col = j * 16 + l16;
#pragma unroll
                for (int r = 0; r < 4; r++)
                    Hsm[rw + r][col] = __float2bfloat16(fmaxf(accP[j][r] + bv[j], 0.f));
            }
        }
        __syncthreads();
        // acc2 += Hsm @ W2c  (W2 fragments from global)
#pragma unroll
        for (int ks = 0; ks < 128; ks += 32) {
            bf16x8 af = *(const bf16x8*)&Hsm[wm + l16][ks + quad * 8];
#pragma unroll
            for (int j = 0; j < 8; j++) {
                bf16x8 bfr = *(const bf16x8*)(w2T +
                    (size_t)(j * 16 + l16) * DFF + c * 128 + ks + quad * 8);
                acc2[j] = __builtin_amdgcn_mfma_f32_16x16x32_bf16(af, bfr, acc2[j], 0, 0, 0);
            }
        }
    }

    // epilogue: out = acc2 + b2 + x; [LN -> outB]; store x
    int rowb = m0 + wm + quad * 4;
    float bv[8];
#pragma unroll
    for (int j = 0; j < 8; j++) bv[j] = b2[j * 16 + l16];
#pragma unroll
    for (int j = 0; j < 8; j++) {
        int col = j * 16 + l16;
#pragma unroll
        for (int r = 0; r < 4; r++) {
            int gr = rowb + r;
            if (gr >= N) continue;
            acc2[j][r] += bv[j] + x[(size_t)gr * D + col];
        }
    }
    if (!DOLN) {
#pragma unroll
        for (int j = 0; j < 8; j++) {
            int col = j * 16 + l16;
#pragma unroll
            for (int r = 0; r < 4; r++) {
                int gr = rowb + r;
                if (gr < N) x[(size_t)gr * D + col] = acc2[j][r];
            }
        }
        return;
    }
    float lsv[8], lbv[8];
#pragma unroll
    for (int j = 0; j < 8; j++) {
        lsv[j] = lns[j * 16 + l16];
        lbv[j] = lnb[j * 16 + l16];
    }
#pragma unroll
    for (int r = 0; r < 4; r++) {
        float s1 = 0.f, s2 = 0.f;
#pragma unroll
        for (int j = 0; j < 8; j++) {
            float v = acc2[j][r];
            s1 += v; s2 += v * v;
        }
        s1 += __shfl_xor(s1, 1, 64);  s2 += __shfl_xor(s2, 1, 64);
        s1 += __shfl_xor(s1, 2, 64);  s2 += __shfl_xor(s2, 2, 64);
        s1 += __shfl_xor(s1, 4, 64);  s2 += __shfl_xor(s2, 4, 64);
        s1 += __shfl_xor(s1, 8, 64);  s2 += __shfl_xor(s2, 8, 64);
        float mu = s1 * (1.f / 128.f);
        float var = s2 * (1.f / 128.f) - mu * mu;
        float rinv = rsqrtf(fmaxf(var, 0.f) + 1e-5f);
        int gr = rowb + r;
        if (gr >= N) continue;
#pragma unroll
        for (int j = 0; j < 8; j++) {
            int col = j * 16 + l16;
            float v = acc2[j][r];
            x[(size_t)gr * D + col] = v;
            outB[(size_t)gr * D + col] = __float2bfloat16((v - mu) * rinv * lsv[j] + lbv[j]);
        }
    }
}

// ---------------- encoder stage 1: hb = bf16(relu(f@w1+b1)) ----------------
__global__ void k_enc1(const float* __restrict__ feat,
                       const float* __restrict__ w1, const float* __restrict__ b1,
                       bf16* __restrict__ hb, int N) {
    __shared__ float fsh[TN][DIN];
    int n0 = blockIdx.x * TN;
    int j = threadIdx.x;            // 0..127
    int nvalid = min(TN, N - n0);
    for (int idx = j; idx < TN * DIN; idx += 128) {
        int n = idx / DIN, i = idx % DIN;
        fsh[n][i] = (n < nvalid) ? feat[(n0 + n) * DIN + i] : 0.f;
    }
    __syncthreads();
    float bb = b1[j];
#pragma unroll
    for (int n = 0; n < TN; n++) {
        float a = bb;
#pragma unroll
        for (int i = 0; i < DIN; i++) a += fsh[n][i] * w1[i * D + j];
        if (n < nvalid) hb[(size_t)(n0 + n) * D + j] = __float2bfloat16(fmaxf(a, 0.f));
    }
}

// ---------------- fused per-receiver softmax attention (8-lane edge-head) ----
__global__ __launch_bounds__(128) void k_attn(
        const bf16* __restrict__ qb, const uint* __restrict__ kvb,
        const int* __restrict__ deg, const int* __restrict__ eid,
        bf16* __restrict__ out, int N) {
    __shared__ float sl[32], sa[32][4];
    int r = blockIdx.x;
    int t = threadIdx.x;
    int wave = t >> 6, lane = t & 63;
    int g = lane & 7;                    // dim group
    int h = (lane >> 3) & 3;             // head
    int slot = wave * 2 + (lane >> 5);   // edge slot 0..3
    int d0 = h * 32 + g * 4;
    uint2 qw = *(const uint2*)(qb + (size_t)r * D + d0);
    float4 qv;
    qv.x = __uint_as_float(qw.x << 16);
    qv.y = __uint_as_float(qw.x & 0xFFFF0000u);
    qv.z = __uint_as_float(qw.y << 16);
    qv.w = __uint_as_float(qw.y & 0xFFFF0000u);
    int cnt = min(deg[r], MAXDEG);
    const int* row = eid + (size_t)r * MAXDEG;
    float l = 0.f, a0 = 0.f, a1 = 0.f, a2 = 0.f, a3 = 0.f;
    for (int base = 0; base < cnt; base += 8) {
        int eiA = base + slot, eiB = base + 4 + slot;
        bool vA = eiA < cnt, vB = eiB < cnt;
        int sA = vA ? row[eiA] : 0;
        int sB = vB ? row[eiB] : 0;
        uint4 wA = *(const uint4*)(kvb + (size_t)sA * D + d0);
        uint4 wB = *(const uint4*)(kvb + (size_t)sB * D + d0);
        {
            float k0 = __uint_as_float(wA.x << 16), v0 = __uint_as_float(wA.x & 0xFFFF0000u);
            float k1 = __uint_as_float(wA.y << 16), v1 = __uint_as_float(wA.y & 0xFFFF0000u);
            float k2 = __uint_as_float(wA.z << 16), v2 = __uint_as_float(wA.z & 0xFFFF0000u);
            float k3 = __uint_as_float(wA.w << 16), v3 = __uint_as_float(wA.w & 0xFFFF0000u);
            float p = qv.x * k0 + qv.y * k1 + qv.z * k2 + qv.w * k3;
            p += __shfl_xor(p, 1, 64);
            p += __shfl_xor(p, 2, 64);
            p += __shfl_xor(p, 4, 64);
            float e = vA ? exp2f(p) : 0.f;
            l += e;
            a0 += e * v0; a1 += e * v1; a2 += e * v2; a3 += e * v3;
        }
        {
            float k0 = __uint_as_float(wB.x << 16), v0 = __uint_as_float(wB.x & 0xFFFF0000u);
            float k1 = __uint_as_float(wB.y << 16), v1 = __uint_as_float(wB.y & 0xFFFF0000u);
            float k2 = __uint_as_float(wB.z << 16), v2 = __uint_as_float(wB.z & 0xFFFF0000u);
            float k3 = __uint_as_float(wB.w << 16), v3 = __uint_as_float(wB.w & 0xFFFF0000u);
            float p = qv.x * k0 + qv.y * k1 + qv.z * k2 + qv.w * k3;
            p += __shfl_xor(p, 1, 64);
            p += __shfl_xor(p, 2, 64);
            p += __shfl_xor(p, 4, 64);
            float e = vB ? exp2f(p) : 0.f;
            l += e;
            a0 += e * v0; a1 += e * v1; a2 += e * v2; a3 += e * v3;
        }
    }
    l  += __shfl_xor(l, 32, 64);
    a0 += __shfl_xor(a0, 32, 64);
    a1 += __shfl_xor(a1, 32, 64);
    a2 += __shfl_xor(a2, 32, 64);
    a3 += __shfl_xor(a3, 32, 64);
    if (wave == 1 && lane < 32) {
        sl[lane] = l;
        sa[lane][0] = a0; sa[lane][1] = a1; sa[lane][2] = a2; sa[lane][3] = a3;
    }
    __syncthreads();
    if (wave == 0 && lane < 32) {
        l += sl[lane];
        float inv = 1.f / (l + 1e-9f);
        bf16 o[4];
        o[0] = __float2bfloat16((a0 + sa[lane][0]) * inv);
        o[1] = __float2bfloat16((a1 + sa[lane][1]) * inv);
        o[2] = __float2bfloat16((a2 + sa[lane][2]) * inv);
        o[3] = __float2bfloat16((a3 + sa[lane][3]) * inv);
        *(uint2*)(out + (size_t)r * D + d0) = *(uint2*)o;
    }
}

// ---------------- decoder: out = relu(x@w1+b1)@w2+b2, wave per node ----------
__global__ void k_decode(const float* __restrict__ x,
                         const float* __restrict__ w1, const float* __restrict__ b1,
                         const float* __restrict__ w2, const float* __restrict__ b2,
                         float* __restrict__ out, int N) {
    int node = blockIdx.x * 4 + (threadIdx.x >> 6);
    int lane = threadIdx.x & 63;
    if (node >= N) return;
    float a0 = x[(size_t)node * D + lane], a1 = x[(size_t)node * D + lane + 64];
    float acc0 = a0 * w1[lane * 3 + 0] + a1 * w1[(lane + 64) * 3 + 0];
    float acc1 = a0 * w1[lane * 3 + 1] + a1 * w1[(lane + 64) * 3 + 1];
    float acc2 = a0 * w1[lane * 3 + 2] + a1 * w1[(lane + 64) * 3 + 2];
#pragma unroll
    for (int m = 32; m >= 1; m >>= 1) {
        acc0 += __shfl_xor(acc0, m, 64);
        acc1 += __shfl_xor(acc1, m, 64);
        acc2 += __shfl_xor(acc2, m, 64);
    }
    if (lane == 0) {
        float t0 = fmaxf(acc0 + b1[0], 0.f);
        float t1 = fmaxf(acc1 + b1[1], 0.f);
        float t2 = fmaxf(acc2 + b1[2], 0.f);
        for (int o = 0; o < 3; o++)
            out[(size_t)node * 3 + o] =
                t0 * w2[0 * 3 + o] + t1 * w2[1 * 3 + o] + t2 * w2[2 * 3 + o] + b2[o];
    }
}

extern "C" void kernel_launch(void* const* d_in, const int* in_sizes, int n_in,
                              void* d_out, int out_size, void* d_ws, size_t ws_size,
                              hipStream_t stream) {
    const float* feat    = (const float*)d_in[0];
    const int*   senders = (const int*)d_in[1];
    const int*   recv    = (const int*)d_in[2];
    const float* enc_w1  = (const float*)d_in[3];
    const float* enc_b1  = (const float*)d_in[4];
    const float* enc_w2  = (const float*)d_in[5];
    const float* enc_b2  = (const float*)d_in[6];
    const float* wq      = (const float*)d_in[7];
    const float* wk      = (const float*)d_in[8];
    const float* wv      = (const float*)d_in[9];
    const float* wo      = (const float*)d_in[10];
    const float* ln1_s   = (const float*)d_in[11];
    const float* ln1_b   = (const float*)d_in[12];
    const float* ffn_w1  = (const float*)d_in[13];
    const float* ffn_b1  = (const float*)d_in[14];
    const float* ffn_w2  = (const float*)d_in[15];
    const float* ffn_b2  = (const float*)d_in[16];
    const float* ln2_s   = (const float*)d_in[17];
    const float* ln2_b   = (const float*)d_in[18];
    const float* dec_w1  = (const float*)d_in[19];
    const float* dec_b1  = (const float*)d_in[20];
    const float* dec_w2  = (const float*)d_in[21];
    const float* dec_b2  = (const float*)d_in[22];

    int N = in_sizes[0] / DIN;
    int E = in_sizes[1];

    // workspace layout
    char* p = (char*)d_ws;
    float* x   = (float*)p;  p += (size_t)N * D * 4;        // residual fp32
    bf16*  qb  = (bf16*)p;   p += (size_t)N * D * 2;        // q bf16 (pre-scaled)
    bf16*  kvb = (bf16*)p;   p += (size_t)N * D * 2 * 2;    // (k,v) bf16 interleaved
    bf16*  hb  = (bf16*)p;   p += (size_t)N * D * 2;        // LN out / attn out bf16
    int* deg   = (int*)p;    p += (size_t)N * 4;
    int* eid   = (int*)p;    p += (size_t)N * MAXDEG * 4;
    bf16* wqkvT  = (bf16*)p; p += (size_t)4 * 3 * D * D * 2;
    bf16* woT    = (bf16*)p; p += (size_t)4 * D * D * 2;
    bf16* w1T    = (bf16*)p; p += (size_t)4 * D * DFF * 2;
    bf16* w2T    = (bf16*)p; p += (size_t)4 * DFF * D * 2;
    bf16* encw2T = (bf16*)p; p += (size_t)D * D * 2;

    int gm = (N + BM - 1) / BM;   // 782

    k_wt<<<dim3(256, 25), 256, 0, stream>>>(wq, wk, wv, wo, ffn_w1, ffn_w2, enc_w2,
                                            wqkvT, woT, w1T, w2T, encw2T);
    k_zero_int<<<(N + 255) / 256, 256, 0, stream>>>(deg, N);
    k_fill<<<(E + 255) / 256, 256, 0, stream>>>(recv, senders, deg, eid, E);
    k_enc1<<<(N + TN - 1) / TN, 128, 0, stream>>>(feat, enc_w1, enc_b1, hb, N);
    // x = hb @ enc_w2 + b2; hb = LN1_0(x)
    k_gemm<5><<<dim3(gm, 1), 256, 0, stream>>>(hb, encw2T, enc_b2,
                                               ln1_s, ln1_b, x, nullptr, hb, N);

    for (int l = 0; l < 4; l++) {
        // qb/kvb from hb
        k_gemm<0><<<dim3(gm, 3), 256, 0, stream>>>(hb, wqkvT + (size_t)l * 3 * D * D,
                                                   nullptr, nullptr, nullptr,
                                                   nullptr, qb, kvb, N);
        k_attn<<<N, 128, 0, stream>>>(qb, (const uint*)kvb, deg, eid, hb, N);
        // x += hb @ wo; hb = LN2(x)
        k_gemm<2><<<dim3(gm, 1), 256, 0, stream>>>(hb, woT + (size_t)l * D * D,
                                                   nullptr, ln2_s + l * D, ln2_b + l * D,
                                                   x, nullptr, hb, N);
        // x += relu(hb@w1+b1)@w2 + b2; [LN1_{l+1} -> hb]
        if (l < 3)
            k_ffn<true><<<gm, 256, 0, stream>>>(hb, w1T + (size_t)l * D * DFF,
                                                ffn_b1 + l * DFF,
                                                w2T + (size_t)l * DFF * D, ffn_b2 + l * D,
                                                ln1_s + (l + 1) * D, ln1_b + (l + 1) * D,
                                                x, hb, N);
        else
            k_ffn<false><<<gm, 256, 0, stream>>>(hb, w1T + (size_t)l * D * DFF,
                                                 ffn_b1 + l * DFF,
                                                 w2T + (size_t)l * DFF * D, ffn_b2 + l * D,
                                                 nullptr, nullptr, x, nullptr, N);
    }
    k_decode<<<(N + 3) / 4, 256, 0, stream>>>(x, dec_w1, dec_b1, dec_w2, dec_b2,
                                              (float*)d_out, N);
}

// Round 10
// 967.801 us; speedup vs baseline: 1.3499x; 1.3499x over previous
//
#include <hip/hip_runtime.h>
#include <hip/hip_bf16.h>
#include <math.h>

#define D     128
#define NHEAD 4
#define DH    32
#define DFF   512
#define DIN   16
#define MAXDEG 64
#define TN    16

typedef __attribute__((ext_vector_type(8))) short bf16x8;
typedef __attribute__((ext_vector_type(4))) float f32x4;
typedef __hip_bfloat16 bf16;

// 1/sqrt(32) * log2(e): q pre-scaled so attn weight = exp2(q.k)
#define QSCALE_L2E 0.2550348838f

// k_ffn LDS pad: 132 bf16 -> quad row-stride 264 dwords = 8 mod 32: C-layout
// scalar writes conflict-free [verified r9: 3.6M -> 100k conflicts].
#define AP 132

// ---------------- CSR build ----------------
__global__ void k_zero_int(int* p, int n) {
    int i = blockIdx.x * blockDim.x + threadIdx.x;
    if (i < n) p[i] = 0;
}

__global__ void k_fill(const int* __restrict__ recv, const int* __restrict__ senders,
                       int* __restrict__ deg, int* __restrict__ eid, int E) {
    int e = blockIdx.x * blockDim.x + threadIdx.x;
    if (e >= E) return;
    int r = recv[e];
    int pos = atomicAdd(&deg[r], 1);
    if (pos < MAXDEG) eid[r * MAXDEG + pos] = senders[e];
}

// ---------------- weight transpose + bf16 convert (one launch, 25 regions) ----
__global__ void k_wt(const float* __restrict__ wq, const float* __restrict__ wk,
                     const float* __restrict__ wv, const float* __restrict__ wo,
                     const float* __restrict__ w1, const float* __restrict__ w2,
                     const float* __restrict__ encw2,
                     bf16* __restrict__ wqkvT, bf16* __restrict__ woT,
                     bf16* __restrict__ w1T, bf16* __restrict__ w2T,
                     bf16* __restrict__ encw2T) {
    int r = blockIdx.y;
    const float* src; bf16* dst; int K, Nout;
    if (r < 12) {
        int l = r / 3, sel = r % 3;
        src = (sel == 0 ? wq : sel == 1 ? wk : wv) + (size_t)l * D * D;
        dst = wqkvT + (size_t)l * 3 * D * D + (size_t)sel * D * D;
        K = D; Nout = D;
    } else if (r < 16) {
        int l = r - 12;
        src = wo + (size_t)l * D * D; dst = woT + (size_t)l * D * D; K = D; Nout = D;
    } else if (r < 20) {
        int l = r - 16;
        src = w1 + (size_t)l * D * DFF; dst = w1T + (size_t)l * D * DFF; K = D; Nout = DFF;
    } else if (r < 24) {
        int l = r - 20;
        src = w2 + (size_t)l * DFF * D; dst = w2T + (size_t)l * DFF * D; K = DFF; Nout = D;
    } else {
        src = encw2; dst = encw2T; K = D; Nout = D;
    }
    int total = K * Nout;
    int i = blockIdx.x * blockDim.x + threadIdx.x;
    if (i >= total) return;
    int k = i / Nout, j = i % Nout;
    dst[(size_t)j * K + k] = __float2bfloat16(src[i]);
}

// ---------------- bf16 MFMA GEMM, BM=64 x BN=128, fused epilogues (r8) ------
// A: [N][K] bf16 row-major. Bt: [Nout][K] bf16; block uses rows
// [y*128, y*128+128) of Bt. 4 waves, wave w owns rows [w*16, w*16+16).
// OPs:
//   0 QKV    : y=0 -> qb bf16 * QSCALE_L2E; y=1 -> k (kvb even); y=2 -> v (odd)
//   2 RES_LN : x += val; LN(x) -> outB          (wo + ln2)
//   5 BIAS_LN: x = val + bias; LN(x) -> outB    (encode + ln1 of layer 0)
#define BM 64
#define BK 64
#define BKP (BK + 8)

template<int OP>
__global__ __launch_bounds__(256) void k_gemm(
        const bf16* A, const bf16* __restrict__ Bt,
        const float* __restrict__ bias,
        const float* __restrict__ lns, const float* __restrict__ lnb,
        float* x, bf16* qb, bf16* outB, int N, int K) {
    __shared__ alignas(16) bf16 Asm[BM][BKP];
    __shared__ alignas(16) bf16 Bsm[128][BKP];
    int m0 = blockIdx.x * BM;
    int y = blockIdx.y;
    const bf16* Bt_ = Bt + (size_t)y * 128 * K;
    int t = threadIdx.x;
    int wave = t >> 6, lane = t & 63;
    int quad = lane >> 4, l16 = lane & 15;
    int wm = wave * 16;

    f32x4 acc[8];
#pragma unroll
    for (int j = 0; j < 8; j++) acc[j] = (f32x4){0.f, 0.f, 0.f, 0.f};

    for (int k0 = 0; k0 < K; k0 += BK) {
        // stage A: 64 x 64 bf16 = 512 x 16B, 2/thread
#pragma unroll
        for (int it = 0; it < 2; it++) {
            int ci = it * 256 + t;
            int rr = ci >> 3, cc = (ci & 7) * 8;
            int gr = m0 + rr;
            uint4 val = make_uint4(0u, 0u, 0u, 0u);
            if (gr < N) val = *(const uint4*)(A + (size_t)gr * K + k0 + cc);
            *(uint4*)&Asm[rr][cc] = val;
        }
        // stage B: 128 x 64 bf16 = 1024 x 16B, 4/thread
#pragma unroll
        for (int it = 0; it < 4; it++) {
            int ci = it * 256 + t;
            int rr = ci >> 3, cc = (ci & 7) * 8;
            *(uint4*)&Bsm[rr][cc] = *(const uint4*)(Bt_ + (size_t)rr * K + k0 + cc);
        }
        __syncthreads();
#pragma unroll
        for (int ks = 0; ks < BK; ks += 32) {
            bf16x8 af = *(const bf16x8*)&Asm[wm + l16][ks + quad * 8];
#pragma unroll
            for (int j = 0; j < 8; j++) {
                bf16x8 bfr = *(const bf16x8*)&Bsm[j * 16 + l16][ks + quad * 8];
                acc[j] = __builtin_amdgcn_mfma_f32_16x16x32_bf16(af, bfr, acc[j], 0, 0, 0);
            }
        }
        __syncthreads();
    }

    // ---- epilogue: C[row = quad*4+reg][col = lane&15] per 16x16 tile ----
    int rowb = m0 + wm + quad * 4;
    if (OP == 0) {             // QKV split
#pragma unroll
        for (int j = 0; j < 8; j++) {
            int col = j * 16 + l16;
#pragma unroll
            for (int r = 0; r < 4; r++) {
                int gr = rowb + r;
                if (gr >= N) continue;
                float val = acc[j][r];
                if (y == 0) qb[(size_t)gr * D + col] = __float2bfloat16(val * QSCALE_L2E);
                else outB[((size_t)gr * D + col) * 2 + (y - 1)] = __float2bfloat16(val);
            }
        }
        return;
    }
    // ---- full-row ops: residual/bias combine + LN ----
    {
        float bv[8];
        if (OP == 5) {
#pragma unroll
            for (int j = 0; j < 8; j++) bv[j] = bias[j * 16 + l16];
        }
#pragma unroll
        for (int j = 0; j < 8; j++) {
            int col = j * 16 + l16;
#pragma unroll
            for (int r = 0; r < 4; r++) {
                int gr = rowb + r;
                if (gr >= N) continue;
                float val = acc[j][r];
                if (OP == 5) val += bv[j];
                if (OP == 2) val += x[(size_t)gr * D + col];
                acc[j][r] = val;
            }
        }
        float lsv[8], lbv[8];
#pragma unroll
        for (int j = 0; j < 8; j++) {
            lsv[j] = lns[j * 16 + l16];
            lbv[j] = lnb[j * 16 + l16];
        }
#pragma unroll
        for (int r = 0; r < 4; r++) {
            float s1 = 0.f, s2 = 0.f;
#pragma unroll
            for (int j = 0; j < 8; j++) {
                float v = acc[j][r];
                s1 += v; s2 += v * v;
            }
            s1 += __shfl_xor(s1, 1, 64);  s2 += __shfl_xor(s2, 1, 64);
            s1 += __shfl_xor(s1, 2, 64);  s2 += __shfl_xor(s2, 2, 64);
            s1 += __shfl_xor(s1, 4, 64);  s2 += __shfl_xor(s2, 4, 64);
            s1 += __shfl_xor(s1, 8, 64);  s2 += __shfl_xor(s2, 8, 64);
            float mu = s1 * (1.f / 128.f);
            float var = s2 * (1.f / 128.f) - mu * mu;
            float rinv = rsqrtf(fmaxf(var, 0.f) + 1e-5f);
            int gr = rowb + r;
            if (gr >= N) continue;
#pragma unroll
            for (int j = 0; j < 8; j++) {
                int col = j * 16 + l16;
                float v = acc[j][r];
                x[(size_t)gr * D + col] = v;
                outB[(size_t)gr * D + col] =
                    __float2bfloat16((v - mu) * rinv * lsv[j] + lbv[j]);
            }
        }
    }
}

// ---------------- fused FFN: x += relu(hb@w1+b1)@w2 + b2 [; LN -> hb] --------
// r8 LDS-staged structure + AP=132 pads + register-prefetch of weight tiles
// (next tile loaded into regs during the MFMA burst on the current tile, then
// committed regs->LDS after the barrier -> global latency overlapped).
template<bool DOLN>
__global__ __launch_bounds__(256) void k_ffn(
        const bf16* hb, const bf16* __restrict__ w1T, const float* __restrict__ b1,
        const bf16* __restrict__ w2T, const float* __restrict__ b2,
        const float* __restrict__ lns, const float* __restrict__ lnb,
        float* x, bf16* outB, int N) {
    __shared__ alignas(16) bf16 Asm[64][AP];     // 16.9 KB
    __shared__ alignas(16) bf16 Wsm[128][AP];    // 33.8 KB (W1c / W2c)
    __shared__ alignas(16) bf16 Hsm[64][AP];     // 16.9 KB
    int m0 = blockIdx.x * 64;
    int t = threadIdx.x;
    int wave = t >> 6, lane = t & 63;
    int quad = lane >> 4, l16 = lane & 15;
    int wm = wave * 16;
    int prr = t >> 1, pcc = (t & 1) * 64;        // this thread's 2 rows? no:
    // prefetch indexing: 2048 x 16B chunks, 8/thread: ci = it*256+t
    (void)prr; (void)pcc;

    // stage A (64 x 128 = 1024 x 16B, 4/thread) + W1 chunk 0 (8/thread)
#pragma unroll
    for (int it = 0; it < 4; it++) {
        int ci = it * 256 + t;
        int rr = ci >> 4, cc = (ci & 15) * 8;
        int gr = m0 + rr;
        uint4 val = make_uint4(0u, 0u, 0u, 0u);
        if (gr < N) val = *(const uint4*)(hb + (size_t)gr * D + cc);
        *(uint4*)&Asm[rr][cc] = val;
    }
#pragma unroll
    for (int it = 0; it < 8; it++) {
        int ci = it * 256 + t;
        int rr = ci >> 4, cc = (ci & 15) * 8;
        *(uint4*)&Wsm[rr][cc] = *(const uint4*)(w1T + (size_t)rr * D + cc);
    }
    __syncthreads();

    // prefetch W2 chunk 0 into registers
    uint4 wreg[8];
#pragma unroll
    for (int it = 0; it < 8; it++) {
        int ci = it * 256 + t;
        int rr = ci >> 4, cc = (ci & 15) * 8;
        wreg[it] = *(const uint4*)(w2T + (size_t)rr * DFF + cc);
    }

    f32x4 acc2[8];
#pragma unroll
    for (int j = 0; j < 8; j++) acc2[j] = (f32x4){0.f, 0.f, 0.f, 0.f};

    for (int c = 0; c < 4; c++) {
        // P = A @ W1c (Wsm holds W1c)
        f32x4 accP[8];
#pragma unroll
        for (int j = 0; j < 8; j++) accP[j] = (f32x4){0.f, 0.f, 0.f, 0.f};
#pragma unroll
        for (int ks = 0; ks < 128; ks += 32) {
            bf16x8 af = *(const bf16x8*)&Asm[wm + l16][ks + quad * 8];
#pragma unroll
            for (int j = 0; j < 8; j++) {
                bf16x8 bfr = *(const bf16x8*)&Wsm[j * 16 + l16][ks + quad * 8];
                accP[j] = __builtin_amdgcn_mfma_f32_16x16x32_bf16(af, bfr, accP[j], 0, 0, 0);
            }
        }
        __syncthreads();   // all waves done reading Wsm(W1c) and Hsm(chunk c-1)
        // commit prefetched W2c regs -> Wsm
#pragma unroll
        for (int it = 0; it < 8; it++) {
            int ci = it * 256 + t;
            int rr = ci >> 4, cc = (ci & 15) * 8;
            *(uint4*)&Wsm[rr][cc] = wreg[it];
        }
        // Hsm = relu(P + b1), C-layout writes (conflict-free at AP=132)
        {
            float bv[8];
#pragma unroll
            for (int j = 0; j < 8; j++) bv[j] = b1[c * 128 + j * 16 + l16];
            int rw = wm + quad * 4;
#pragma unroll
            for (int j = 0; j < 8; j++) {
                int col = j * 16 + l16;
#pragma unroll
                for (int r = 0; r < 4; r++)
                    Hsm[rw + r][col] = __float2bfloat16(fmaxf(accP[j][r] + bv[j], 0.f));
            }
        }
        // prefetch next W1 chunk (overlaps barrier + MFMA2)
        if (c < 3) {
#pragma unroll
            for (int it = 0; it < 8; it++) {
                int ci = it * 256 + t;
                int rr = ci >> 4, cc = (ci & 15) * 8;
                wreg[it] = *(const uint4*)(w1T + (size_t)((c + 1) * 128 + rr) * D + cc);
            }
        }
        __syncthreads();   // Wsm(W2c) + Hsm visible
        // acc2 += Hsm @ W2c
#pragma unroll
        for (int ks = 0; ks < 128; ks += 32) {
            bf16x8 af = *(const bf16x8*)&Hsm[wm + l16][ks + quad * 8];
#pragma unroll
            for (int j = 0; j < 8; j++) {
                bf16x8 bfr = *(const bf16x8*)&Wsm[j * 16 + l16][ks + quad * 8];
                acc2[j] = __builtin_amdgcn_mfma_f32_16x16x32_bf16(af, bfr, acc2[j], 0, 0, 0);
            }
        }
        if (c < 3) {
            __syncthreads();  // done reading Wsm(W2c)
            // commit prefetched W1(next) regs -> Wsm
#pragma unroll
            for (int it = 0; it < 8; it++) {
                int ci = it * 256 + t;
                int rr = ci >> 4, cc = (ci & 15) * 8;
                *(uint4*)&Wsm[rr][cc] = wreg[it];
            }
            // prefetch W2(next) into regs (overlaps barrier + MFMA1)
#pragma unroll
            for (int it = 0; it < 8; it++) {
                int ci = it * 256 + t;
                int rr = ci >> 4, cc = (ci & 15) * 8;
                wreg[it] = *(const uint4*)(w2T + (size_t)rr * DFF + (c + 1) * 128 + cc);
            }
            __syncthreads();  // Wsm(W1 next) visible
        }
    }

    // epilogue: out = acc2 + b2 + x; [LN -> outB]; store x
    int rowb = m0 + wm + quad * 4;
    float bv[8];
#pragma unroll
    for (int j = 0; j < 8; j++) bv[j] = b2[j * 16 + l16];
#pragma unroll
    for (int j = 0; j < 8; j++) {
        int col = j * 16 + l16;
#pragma unroll
        for (int r = 0; r < 4; r++) {
            int gr = rowb + r;
            if (gr >= N) continue;
            acc2[j][r] += bv[j] + x[(size_t)gr * D + col];
        }
    }
    if (!DOLN) {
#pragma unroll
        for (int j = 0; j < 8; j++) {
            int col = j * 16 + l16;
#pragma unroll
            for (int r = 0; r < 4; r++) {
                int gr = rowb + r;
                if (gr < N) x[(size_t)gr * D + col] = acc2[j][r];
            }
        }
        return;
    }
    float lsv[8], lbv[8];
#pragma unroll
    for (int j = 0; j < 8; j++) {
        lsv[j] = lns[j * 16 + l16];
        lbv[j] = lnb[j * 16 + l16];
    }
#pragma unroll
    for (int r = 0; r < 4; r++) {
        float s1 = 0.f, s2 = 0.f;
#pragma unroll
        for (int j = 0; j < 8; j++) {
            float v = acc2[j][r];
            s1 += v; s2 += v * v;
        }
        s1 += __shfl_xor(s1, 1, 64);  s2 += __shfl_xor(s2, 1, 64);
        s1 += __shfl_xor(s1, 2, 64);  s2 += __shfl_xor(s2, 2, 64);
        s1 += __shfl_xor(s1, 4, 64);  s2 += __shfl_xor(s2, 4, 64);
        s1 += __shfl_xor(s1, 8, 64);  s2 += __shfl_xor(s2, 8, 64);
        float mu = s1 * (1.f / 128.f);
        float var = s2 * (1.f / 128.f) - mu * mu;
        float rinv = rsqrtf(fmaxf(var, 0.f) + 1e-5f);
        int gr = rowb + r;
        if (gr >= N) continue;
#pragma unroll
        for (int j = 0; j < 8; j++) {
            int col = j * 16 + l16;
            float v = acc2[j][r];
            x[(size_t)gr * D + col] = v;
            outB[(size_t)gr * D + col] = __float2bfloat16((v - mu) * rinv * lsv[j] + lbv[j]);
        }
    }
}

// ---------------- encoder stage 1: hb = bf16(relu(f@w1+b1)) ----------------
__global__ void k_enc1(const float* __restrict__ feat,
                       const float* __restrict__ w1, const float* __restrict__ b1,
                       bf16* __restrict__ hb, int N) {
    __shared__ float fsh[TN][DIN];
    int n0 = blockIdx.x * TN;
    int j = threadIdx.x;            // 0..127
    int nvalid = min(TN, N - n0);
    for (int idx = j; idx < TN * DIN; idx += 128) {
        int n = idx / DIN, i = idx % DIN;
        fsh[n][i] = (n < nvalid) ? feat[(n0 + n) * DIN + i] : 0.f;
    }
    __syncthreads();
    float bb = b1[j];
#pragma unroll
    for (int n = 0; n < TN; n++) {
        float a = bb;
#pragma unroll
        for (int i = 0; i < DIN; i++) a += fsh[n][i] * w1[i * D + j];
        if (n < nvalid) hb[(size_t)(n0 + n) * D + j] = __float2bfloat16(fmaxf(a, 0.f));
    }
}

// ---------------- fused per-receiver softmax attention (8-lane edge-head) ----
__global__ __launch_bounds__(128) void k_attn(
        const bf16* __restrict__ qb, const uint* __restrict__ kvb,
        const int* __restrict__ deg, const int* __restrict__ eid,
        bf16* __restrict__ out, int N) {
    __shared__ float sl[32], sa[32][4];
    int r = blockIdx.x;
    int t = threadIdx.x;
    int wave = t >> 6, lane = t & 63;
    int g = lane & 7;                    // dim group
    int h = (lane >> 3) & 3;             // head
    int slot = wave * 2 + (lane >> 5);   // edge slot 0..3
    int d0 = h * 32 + g * 4;
    uint2 qw = *(const uint2*)(qb + (size_t)r * D + d0);
    float4 qv;
    qv.x = __uint_as_float(qw.x << 16);
    qv.y = __uint_as_float(qw.x & 0xFFFF0000u);
    qv.z = __uint_as_float(qw.y << 16);
    qv.w = __uint_as_float(qw.y & 0xFFFF0000u);
    int cnt = min(deg[r], MAXDEG);
    const int* row = eid + (size_t)r * MAXDEG;
    float l = 0.f, a0 = 0.f, a1 = 0.f, a2 = 0.f, a3 = 0.f;
    for (int base = 0; base < cnt; base += 8) {
        int eiA = base + slot, eiB = base + 4 + slot;
        bool vA = eiA < cnt, vB = eiB < cnt;
        int sA = vA ? row[eiA] : 0;
        int sB = vB ? row[eiB] : 0;
        uint4 wA = *(const uint4*)(kvb + (size_t)sA * D + d0);
        uint4 wB = *(const uint4*)(kvb + (size_t)sB * D + d0);
        {
            float k0 = __uint_as_float(wA.x << 16), v0 = __uint_as_float(wA.x & 0xFFFF0000u);
            float k1 = __uint_as_float(wA.y << 16), v1 = __uint_as_float(wA.y & 0xFFFF0000u);
            float k2 = __uint_as_float(wA.z << 16), v2 = __uint_as_float(wA.z & 0xFFFF0000u);
            float k3 = __uint_as_float(wA.w << 16), v3 = __uint_as_float(wA.w & 0xFFFF0000u);
            float p = qv.x * k0 + qv.y * k1 + qv.z * k2 + qv.w * k3;
            p += __shfl_xor(p, 1, 64);
            p += __shfl_xor(p, 2, 64);
            p += __shfl_xor(p, 4, 64);
            float e = vA ? exp2f(p) : 0.f;
            l += e;
            a0 += e * v0; a1 += e * v1; a2 += e * v2; a3 += e * v3;
        }
        {
            float k0 = __uint_as_float(wB.x << 16), v0 = __uint_as_float(wB.x & 0xFFFF0000u);
            float k1 = __uint_as_float(wB.y << 16), v1 = __uint_as_float(wB.y & 0xFFFF0000u);
            float k2 = __uint_as_float(wB.z << 16), v2 = __uint_as_float(wB.z & 0xFFFF0000u);
            float k3 = __uint_as_float(wB.w << 16), v3 = __uint_as_float(wB.w & 0xFFFF0000u);
            float p = qv.x * k0 + qv.y * k1 + qv.z * k2 + qv.w * k3;
            p += __shfl_xor(p, 1, 64);
            p += __shfl_xor(p, 2, 64);
            p += __shfl_xor(p, 4, 64);
            float e = vB ? exp2f(p) : 0.f;
            l += e;
            a0 += e * v0; a1 += e * v1; a2 += e * v2; a3 += e * v3;
        }
    }
    l  += __shfl_xor(l, 32, 64);
    a0 += __shfl_xor(a0, 32, 64);
    a1 += __shfl_xor(a1, 32, 64);
    a2 += __shfl_xor(a2, 32, 64);
    a3 += __shfl_xor(a3, 32, 64);
    if (wave == 1 && lane < 32) {
        sl[lane] = l;
        sa[lane][0] = a0; sa[lane][1] = a1; sa[lane][2] = a2; sa[lane][3] = a3;
    }
    __syncthreads();
    if (wave == 0 && lane < 32) {
        l += sl[lane];
        float inv = 1.f / (l + 1e-9f);
        bf16 o[4];
        o[0] = __float2bfloat16((a0 + sa[lane][0]) * inv);
        o[1] = __float2bfloat16((a1 + sa[lane][1]) * inv);
        o[2] = __float2bfloat16((a2 + sa[lane][2]) * inv);
        o[3] = __float2bfloat16((a3 + sa[lane][3]) * inv);
        *(uint2*)(out + (size_t)r * D + d0) = *(uint2*)o;
    }
}

// ---------------- decoder: out = relu(x@w1+b1)@w2+b2, wave per node ----------
__global__ void k_decode(const float* __restrict__ x,
                         const float* __restrict__ w1, const float* __restrict__ b1,
                         const float* __restrict__ w2, const float* __restrict__ b2,
                         float* __restrict__ out, int N) {
    int node = blockIdx.x * 4 + (threadIdx.x >> 6);
    int lane = threadIdx.x & 63;
    if (node >= N) return;
    float a0 = x[(size_t)node * D + lane], a1 = x[(size_t)node * D + lane + 64];
    float acc0 = a0 * w1[lane * 3 + 0] + a1 * w1[(lane + 64) * 3 + 0];
    float acc1 = a0 * w1[lane * 3 + 1] + a1 * w1[(lane + 64) * 3 + 1];
    float acc2 = a0 * w1[lane * 3 + 2] + a1 * w1[(lane + 64) * 3 + 2];
#pragma unroll
    for (int m = 32; m >= 1; m >>= 1) {
        acc0 += __shfl_xor(acc0, m, 64);
        acc1 += __shfl_xor(acc1, m, 64);
        acc2 += __shfl_xor(acc2, m, 64);
    }
    if (lane == 0) {
        float t0 = fmaxf(acc0 + b1[0], 0.f);
        float t1 = fmaxf(acc1 + b1[1], 0.f);
        float t2 = fmaxf(acc2 + b1[2], 0.f);
        for (int o = 0; o < 3; o++)
            out[(size_t)node * 3 + o] =
                t0 * w2[0 * 3 + o] + t1 * w2[1 * 3 + o] + t2 * w2[2 * 3 + o] + b2[o];
    }
}

extern "C" void kernel_launch(void* const* d_in, const int* in_sizes, int n_in,
                              void* d_out, int out_size, void* d_ws, size_t ws_size,
                              hipStream_t stream) {
    const float* feat    = (const float*)d_in[0];
    const int*   senders = (const int*)d_in[1];
    const int*   recv    = (const int*)d_in[2];
    const float* enc_w1  = (const float*)d_in[3];
    const float* enc_b1  = (const float*)d_in[4];
    const float* enc_w2  = (const float*)d_in[5];
    const float* enc_b2  = (const float*)d_in[6];
    const float* wq      = (const float*)d_in[7];
    const float* wk      = (const float*)d_in[8];
    const float* wv      = (const float*)d_in[9];
    const float* wo      = (const float*)d_in[10];
    const float* ln1_s   = (const float*)d_in[11];
    const float* ln1_b   = (const float*)d_in[12];
    const float* ffn_w1  = (const float*)d_in[13];
    const float* ffn_b1  = (const float*)d_in[14];
    const float* ffn_w2  = (const float*)d_in[15];
    const float* ffn_b2  = (const float*)d_in[16];
    const float* ln2_s   = (const float*)d_in[17];
    const float* ln2_b   = (const float*)d_in[18];
    const float* dec_w1  = (const float*)d_in[19];
    const float* dec_b1  = (const float*)d_in[20];
    const float* dec_w2  = (const float*)d_in[21];
    const float* dec_b2  = (const float*)d_in[22];

    int N = in_sizes[0] / DIN;
    int E = in_sizes[1];

    // workspace layout
    char* p = (char*)d_ws;
    float* x   = (float*)p;  p += (size_t)N * D * 4;        // residual fp32
    bf16*  qb  = (bf16*)p;   p += (size_t)N * D * 2;        // q bf16 (pre-scaled)
    bf16*  kvb = (bf16*)p;   p += (size_t)N * D * 2 * 2;    // (k,v) bf16 interleaved
    bf16*  hb  = (bf16*)p;   p += (size_t)N * D * 2;        // LN out / attn out bf16
    int* deg   = (int*)p;    p += (size_t)N * 4;
    int* eid   = (int*)p;    p += (size_t)N * MAXDEG * 4;
    bf16* wqkvT  = (bf16*)p; p += (size_t)4 * 3 * D * D * 2;
    bf16* woT    = (bf16*)p; p += (size_t)4 * D * D * 2;
    bf16* w1T    = (bf16*)p; p += (size_t)4 * D * DFF * 2;
    bf16* w2T    = (bf16*)p; p += (size_t)4 * DFF * D * 2;
    bf16* encw2T = (bf16*)p; p += (size_t)D * D * 2;

    int gm = (N + BM - 1) / BM;   // 782

    k_wt<<<dim3(256, 25), 256, 0, stream>>>(wq, wk, wv, wo, ffn_w1, ffn_w2, enc_w2,
                                            wqkvT, woT, w1T, w2T, encw2T);
    k_zero_int<<<(N + 255) / 256, 256, 0, stream>>>(deg, N);
    k_fill<<<(E + 255) / 256, 256, 0, stream>>>(recv, senders, deg, eid, E);
    k_enc1<<<(N + TN - 1) / TN, 128, 0, stream>>>(feat, enc_w1, enc_b1, hb, N);
    // x = hb @ enc_w2 + b2; hb = LN1_0(x)
    k_gemm<5><<<dim3(gm, 1), 256, 0, stream>>>(hb, encw2T, enc_b2,
                                               ln1_s, ln1_b, x, nullptr, hb, N, D);

    for (int l = 0; l < 4; l++) {
        // qb/kvb from hb
        k_gemm<0><<<dim3(gm, 3), 256, 0, stream>>>(hb, wqkvT + (size_t)l * 3 * D * D,
                                                   nullptr, nullptr, nullptr,
                                                   nullptr, qb, kvb, N, D);
        k_attn<<<N, 128, 0, stream>>>(qb, (const uint*)kvb, deg, eid, hb, N);
        // x += hb @ wo; hb = LN2(x)
        k_gemm<2><<<dim3(gm, 1), 256, 0, stream>>>(hb, woT + (size_t)l * D * D,
                                                   nullptr, ln2_s + l * D, ln2_b + l * D,
                                                   x, nullptr, hb, N, D);
        // x += relu(hb@w1+b1)@w2 + b2; [LN1_{l+1} -> hb]
        if (l < 3)
            k_ffn<true><<<gm, 256, 0, stream>>>(hb, w1T + (size_t)l * D * DFF,
                                                ffn_b1 + l * DFF,
                                                w2T + (size_t)l * DFF * D, ffn_b2 + l * D,
                                                ln1_s + (l + 1) * D, ln1_b + (l + 1) * D,
                                                x, hb, N);
        else
            k_ffn<false><<<gm, 256, 0, stream>>>(hb, w1T + (size_t)l * D * DFF,
                                                 ffn_b1 + l * DFF,
                                                 w2T + (size_t)l * DFF * D, ffn_b2 + l * D,
                                                 nullptr, nullptr, x, nullptr, N);
    }
    k_decode<<<(N + 3) / 4, 256, 0, stream>>>(x, dec_w1, dec_b1, dec_w2, dec_b2,
                                              (float*)d_out, N);
}

// Round 11
// 783.346 us; speedup vs baseline: 1.6678x; 1.2355x over previous
//
#include <hip/hip_runtime.h>
#include <hip/hip_bf16.h>
#include <math.h>

#define D     128
#define NHEAD 4
#define DH    32
#define DFF   512
#define DIN   16
#define MAXDEG 64
#define TN    16

typedef __attribute__((ext_vector_type(8))) short bf16x8;
typedef __attribute__((ext_vector_type(4))) float f32x4;
typedef __hip_bfloat16 bf16;

// 1/sqrt(32) * log2(e): q pre-scaled so attn weight = exp2(q.k)
#define QSCALE_L2E 0.2550348838f

// k_ffn LDS pad: 132 bf16 -> quad row-stride 264 dwords = 8 mod 32: C-layout
// scalar writes conflict-free [verified r9: 3.6M -> 100k conflicts].
// NOTE r10: register-prefetch of weight tiles spills (WRITE_SIZE 25->104MB) — do not.
#define AP 132

// ---------------- CSR build ----------------
__global__ void k_zero_int(int* p, int n) {
    int i = blockIdx.x * blockDim.x + threadIdx.x;
    if (i < n) p[i] = 0;
}

__global__ void k_fill(const int* __restrict__ recv, const int* __restrict__ senders,
                       int* __restrict__ deg, int* __restrict__ eid, int E) {
    int e = blockIdx.x * blockDim.x + threadIdx.x;
    if (e >= E) return;
    int r = recv[e];
    int pos = atomicAdd(&deg[r], 1);
    if (pos < MAXDEG) eid[r * MAXDEG + pos] = senders[e];
}

// ---------------- weight transpose + bf16 convert (one launch, 25 regions) ----
__global__ void k_wt(const float* __restrict__ wq, const float* __restrict__ wk,
                     const float* __restrict__ wv, const float* __restrict__ wo,
                     const float* __restrict__ w1, const float* __restrict__ w2,
                     const float* __restrict__ encw2,
                     bf16* __restrict__ wqkvT, bf16* __restrict__ woT,
                     bf16* __restrict__ w1T, bf16* __restrict__ w2T,
                     bf16* __restrict__ encw2T) {
    int r = blockIdx.y;
    const float* src; bf16* dst; int K, Nout;
    if (r < 12) {
        int l = r / 3, sel = r % 3;
        src = (sel == 0 ? wq : sel == 1 ? wk : wv) + (size_t)l * D * D;
        dst = wqkvT + (size_t)l * 3 * D * D + (size_t)sel * D * D;
        K = D; Nout = D;
    } else if (r < 16) {
        int l = r - 12;
        src = wo + (size_t)l * D * D; dst = woT + (size_t)l * D * D; K = D; Nout = D;
    } else if (r < 20) {
        int l = r - 16;
        src = w1 + (size_t)l * D * DFF; dst = w1T + (size_t)l * D * DFF; K = D; Nout = DFF;
    } else if (r < 24) {
        int l = r - 20;
        src = w2 + (size_t)l * DFF * D; dst = w2T + (size_t)l * DFF * D; K = DFF; Nout = D;
    } else {
        src = encw2; dst = encw2T; K = D; Nout = D;
    }
    int total = K * Nout;
    int i = blockIdx.x * blockDim.x + threadIdx.x;
    if (i >= total) return;
    int k = i / Nout, j = i % Nout;
    dst[(size_t)j * K + k] = __float2bfloat16(src[i]);
}

// ---------------- bf16 MFMA GEMM, BM=64 x BN=128, fused epilogues (r8) ------
// OPs:
//   0 QKV    : y=0 -> qb bf16 * QSCALE_L2E; y=1 -> k (kvb even); y=2 -> v (odd)
//   2 RES_LN : x += val; LN(x) -> outB          (wo + ln2)
//   5 BIAS_LN: x = val + bias; LN(x) -> outB    (encode + ln1 of layer 0)
#define BM 64
#define BK 64
#define BKP (BK + 8)

template<int OP>
__global__ __launch_bounds__(256) void k_gemm(
        const bf16* A, const bf16* __restrict__ Bt,
        const float* __restrict__ bias,
        const float* __restrict__ lns, const float* __restrict__ lnb,
        float* x, bf16* qb, bf16* outB, int N, int K) {
    __shared__ alignas(16) bf16 Asm[BM][BKP];
    __shared__ alignas(16) bf16 Bsm[128][BKP];
    int m0 = blockIdx.x * BM;
    int y = blockIdx.y;
    const bf16* Bt_ = Bt + (size_t)y * 128 * K;
    int t = threadIdx.x;
    int wave = t >> 6, lane = t & 63;
    int quad = lane >> 4, l16 = lane & 15;
    int wm = wave * 16;

    f32x4 acc[8];
#pragma unroll
    for (int j = 0; j < 8; j++) acc[j] = (f32x4){0.f, 0.f, 0.f, 0.f};

    for (int k0 = 0; k0 < K; k0 += BK) {
#pragma unroll
        for (int it = 0; it < 2; it++) {
            int ci = it * 256 + t;
            int rr = ci >> 3, cc = (ci & 7) * 8;
            int gr = m0 + rr;
            uint4 val = make_uint4(0u, 0u, 0u, 0u);
            if (gr < N) val = *(const uint4*)(A + (size_t)gr * K + k0 + cc);
            *(uint4*)&Asm[rr][cc] = val;
        }
#pragma unroll
        for (int it = 0; it < 4; it++) {
            int ci = it * 256 + t;
            int rr = ci >> 3, cc = (ci & 7) * 8;
            *(uint4*)&Bsm[rr][cc] = *(const uint4*)(Bt_ + (size_t)rr * K + k0 + cc);
        }
        __syncthreads();
#pragma unroll
        for (int ks = 0; ks < BK; ks += 32) {
            bf16x8 af = *(const bf16x8*)&Asm[wm + l16][ks + quad * 8];
#pragma unroll
            for (int j = 0; j < 8; j++) {
                bf16x8 bfr = *(const bf16x8*)&Bsm[j * 16 + l16][ks + quad * 8];
                acc[j] = __builtin_amdgcn_mfma_f32_16x16x32_bf16(af, bfr, acc[j], 0, 0, 0);
            }
        }
        __syncthreads();
    }

    // ---- epilogue: C[row = quad*4+reg][col = lane&15] per 16x16 tile ----
    int rowb = m0 + wm + quad * 4;
    if (OP == 0) {             // QKV split
#pragma unroll
        for (int j = 0; j < 8; j++) {
            int col = j * 16 + l16;
#pragma unroll
            for (int r = 0; r < 4; r++) {
                int gr = rowb + r;
                if (gr >= N) continue;
                float val = acc[j][r];
                if (y == 0) qb[(size_t)gr * D + col] = __float2bfloat16(val * QSCALE_L2E);
                else outB[((size_t)gr * D + col) * 2 + (y - 1)] = __float2bfloat16(val);
            }
        }
        return;
    }
    // ---- full-row ops: residual/bias combine + LN ----
    {
        float bv[8];
        if (OP == 5) {
#pragma unroll
            for (int j = 0; j < 8; j++) bv[j] = bias[j * 16 + l16];
        }
#pragma unroll
        for (int j = 0; j < 8; j++) {
            int col = j * 16 + l16;
#pragma unroll
            for (int r = 0; r < 4; r++) {
                int gr = rowb + r;
                if (gr >= N) continue;
                float val = acc[j][r];
                if (OP == 5) val += bv[j];
                if (OP == 2) val += x[(size_t)gr * D + col];
                acc[j][r] = val;
            }
        }
        float lsv[8], lbv[8];
#pragma unroll
        for (int j = 0; j < 8; j++) {
            lsv[j] = lns[j * 16 + l16];
            lbv[j] = lnb[j * 16 + l16];
        }
#pragma unroll
        for (int r = 0; r < 4; r++) {
            float s1 = 0.f, s2 = 0.f;
#pragma unroll
            for (int j = 0; j < 8; j++) {
                float v = acc[j][r];
                s1 += v; s2 += v * v;
            }
            s1 += __shfl_xor(s1, 1, 64);  s2 += __shfl_xor(s2, 1, 64);
            s1 += __shfl_xor(s1, 2, 64);  s2 += __shfl_xor(s2, 2, 64);
            s1 += __shfl_xor(s1, 4, 64);  s2 += __shfl_xor(s2, 4, 64);
            s1 += __shfl_xor(s1, 8, 64);  s2 += __shfl_xor(s2, 8, 64);
            float mu = s1 * (1.f / 128.f);
            float var = s2 * (1.f / 128.f) - mu * mu;
            float rinv = rsqrtf(fmaxf(var, 0.f) + 1e-5f);
            int gr = rowb + r;
            if (gr >= N) continue;
#pragma unroll
            for (int j = 0; j < 8; j++) {
                int col = j * 16 + l16;
                float v = acc[j][r];
                x[(size_t)gr * D + col] = v;
                outB[(size_t)gr * D + col] =
                    __float2bfloat16((v - mu) * rinv * lsv[j] + lbv[j]);
            }
        }
    }
}

// ---------------- fused FFN: x += relu(hb@w1+b1)@w2 + b2 [; LN -> hb] --------
// r8 structure (LDS-staged weight chunks, no reg prefetch) + AP=132 pads.
template<bool DOLN>
__global__ __launch_bounds__(256) void k_ffn(
        const bf16* hb, const bf16* __restrict__ w1T, const float* __restrict__ b1,
        const bf16* __restrict__ w2T, const float* __restrict__ b2,
        const float* __restrict__ lns, const float* __restrict__ lnb,
        float* x, bf16* outB, int N) {
    __shared__ alignas(16) bf16 Asm[64][AP];     // 16.9 KB
    __shared__ alignas(16) bf16 Wsm[128][AP];    // 33.8 KB (W1c / W2c)
    __shared__ alignas(16) bf16 Hsm[64][AP];     // 16.9 KB
    int m0 = blockIdx.x * 64;
    int t = threadIdx.x;
    int wave = t >> 6, lane = t & 63;
    int quad = lane >> 4, l16 = lane & 15;
    int wm = wave * 16;

    // stage A: 64 x 128 = 1024 x 16B, 4/thread
#pragma unroll
    for (int it = 0; it < 4; it++) {
        int ci = it * 256 + t;
        int rr = ci >> 4, cc = (ci & 15) * 8;
        int gr = m0 + rr;
        uint4 val = make_uint4(0u, 0u, 0u, 0u);
        if (gr < N) val = *(const uint4*)(hb + (size_t)gr * D + cc);
        *(uint4*)&Asm[rr][cc] = val;
    }
    // stage W1 chunk 0: 128 x 128 = 2048 x 16B, 8/thread
#pragma unroll
    for (int it = 0; it < 8; it++) {
        int ci = it * 256 + t;
        int rr = ci >> 4, cc = (ci & 15) * 8;
        *(uint4*)&Wsm[rr][cc] = *(const uint4*)(w1T + (size_t)rr * D + cc);
    }
    __syncthreads();

    f32x4 acc2[8];
#pragma unroll
    for (int j = 0; j < 8; j++) acc2[j] = (f32x4){0.f, 0.f, 0.f, 0.f};

    for (int c = 0; c < 4; c++) {
        // P = A @ W1c
        f32x4 accP[8];
#pragma unroll
        for (int j = 0; j < 8; j++) accP[j] = (f32x4){0.f, 0.f, 0.f, 0.f};
#pragma unroll
        for (int ks = 0; ks < 128; ks += 32) {
            bf16x8 af = *(const bf16x8*)&Asm[wm + l16][ks + quad * 8];
#pragma unroll
            for (int j = 0; j < 8; j++) {
                bf16x8 bfr = *(const bf16x8*)&Wsm[j * 16 + l16][ks + quad * 8];
                accP[j] = __builtin_amdgcn_mfma_f32_16x16x32_bf16(af, bfr, accP[j], 0, 0, 0);
            }
        }
        __syncthreads();   // done reading Wsm (W1c) and Hsm (prev chunk)
        // stage W2c: 128 out-cols x 128 K-slice, 8/thread
#pragma unroll
        for (int it = 0; it < 8; it++) {
            int ci = it * 256 + t;
            int rr = ci >> 4, cc = (ci & 15) * 8;
            *(uint4*)&Wsm[rr][cc] = *(const uint4*)(w2T + (size_t)rr * DFF + c * 128 + cc);
        }
        // write Hsm = relu(P + b1) in A-layout [m][k] (conflict-free @ AP=132)
        {
            float bv[8];
#pragma unroll
            for (int j = 0; j < 8; j++) bv[j] = b1[c * 128 + j * 16 + l16];
            int rw = wm + quad * 4;
#pragma unroll
            for (int j = 0; j < 8; j++) {
                int col = j * 16 + l16;
#pragma unroll
                for (int r = 0; r < 4; r++)
                    Hsm[rw + r][col] = __float2bfloat16(fmaxf(accP[j][r] + bv[j], 0.f));
            }
        }
        __syncthreads();
        // acc2 += Hsm @ W2c
#pragma unroll
        for (int ks = 0; ks < 128; ks += 32) {
            bf16x8 af = *(const bf16x8*)&Hsm[wm + l16][ks + quad * 8];
#pragma unroll
            for (int j = 0; j < 8; j++) {
                bf16x8 bfr = *(const bf16x8*)&Wsm[j * 16 + l16][ks + quad * 8];
                acc2[j] = __builtin_amdgcn_mfma_f32_16x16x32_bf16(af, bfr, acc2[j], 0, 0, 0);
            }
        }
        if (c < 3) {
            __syncthreads();  // done reading Wsm (W2c)
#pragma unroll
            for (int it = 0; it < 8; it++) {
                int ci = it * 256 + t;
                int rr = ci >> 4, cc = (ci & 15) * 8;
                *(uint4*)&Wsm[rr][cc] =
                    *(const uint4*)(w1T + (size_t)((c + 1) * 128 + rr) * D + cc);
            }
            __syncthreads();
        }
    }

    // epilogue: out = acc2 + b2 + x; [LN -> outB]; store x
    int rowb = m0 + wm + quad * 4;
    float bv[8];
#pragma unroll
    for (int j = 0; j < 8; j++) bv[j] = b2[j * 16 + l16];
#pragma unroll
    for (int j = 0; j < 8; j++) {
        int col = j * 16 + l16;
#pragma unroll
        for (int r = 0; r < 4; r++) {
            int gr = rowb + r;
            if (gr >= N) continue;
            acc2[j][r] += bv[j] + x[(size_t)gr * D + col];
        }
    }
    if (!DOLN) {
#pragma unroll
        for (int j = 0; j < 8; j++) {
            int col = j * 16 + l16;
#pragma unroll
            for (int r = 0; r < 4; r++) {
                int gr = rowb + r;
                if (gr < N) x[(size_t)gr * D + col] = acc2[j][r];
            }
        }
        return;
    }
    float lsv[8], lbv[8];
#pragma unroll
    for (int j = 0; j < 8; j++) {
        lsv[j] = lns[j * 16 + l16];
        lbv[j] = lnb[j * 16 + l16];
    }
#pragma unroll
    for (int r = 0; r < 4; r++) {
        float s1 = 0.f, s2 = 0.f;
#pragma unroll
        for (int j = 0; j < 8; j++) {
            float v = acc2[j][r];
            s1 += v; s2 += v * v;
        }
        s1 += __shfl_xor(s1, 1, 64);  s2 += __shfl_xor(s2, 1, 64);
        s1 += __shfl_xor(s1, 2, 64);  s2 += __shfl_xor(s2, 2, 64);
        s1 += __shfl_xor(s1, 4, 64);  s2 += __shfl_xor(s2, 4, 64);
        s1 += __shfl_xor(s1, 8, 64);  s2 += __shfl_xor(s2, 8, 64);
        float mu = s1 * (1.f / 128.f);
        float var = s2 * (1.f / 128.f) - mu * mu;
        float rinv = rsqrtf(fmaxf(var, 0.f) + 1e-5f);
        int gr = rowb + r;
        if (gr >= N) continue;
#pragma unroll
        for (int j = 0; j < 8; j++) {
            int col = j * 16 + l16;
            float v = acc2[j][r];
            x[(size_t)gr * D + col] = v;
            outB[(size_t)gr * D + col] = __float2bfloat16((v - mu) * rinv * lsv[j] + lbv[j]);
        }
    }
}

// ---------------- encoder stage 1: hb = bf16(relu(f@w1+b1)) ----------------
__global__ void k_enc1(const float* __restrict__ feat,
                       const float* __restrict__ w1, const float* __restrict__ b1,
                       bf16* __restrict__ hb, int N) {
    __shared__ float fsh[TN][DIN];
    int n0 = blockIdx.x * TN;
    int j = threadIdx.x;            // 0..127
    int nvalid = min(TN, N - n0);
    for (int idx = j; idx < TN * DIN; idx += 128) {
        int n = idx / DIN, i = idx % DIN;
        fsh[n][i] = (n < nvalid) ? feat[(n0 + n) * DIN + i] : 0.f;
    }
    __syncthreads();
    float bb = b1[j];
#pragma unroll
    for (int n = 0; n < TN; n++) {
        float a = bb;
#pragma unroll
        for (int i = 0; i < DIN; i++) a += fsh[n][i] * w1[i * D + j];
        if (n < nvalid) hb[(size_t)(n0 + n) * D + j] = __float2bfloat16(fmaxf(a, 0.f));
    }
}

// ---------------- fused per-receiver softmax attention (8-lane edge-head) ----
__global__ __launch_bounds__(128) void k_attn(
        const bf16* __restrict__ qb, const uint* __restrict__ kvb,
        const int* __restrict__ deg, const int* __restrict__ eid,
        bf16* __restrict__ out, int N) {
    __shared__ float sl[32], sa[32][4];
    int r = blockIdx.x;
    int t = threadIdx.x;
    int wave = t >> 6, lane = t & 63;
    int g = lane & 7;                    // dim group
    int h = (lane >> 3) & 3;             // head
    int slot = wave * 2 + (lane >> 5);   // edge slot 0..3
    int d0 = h * 32 + g * 4;
    uint2 qw = *(const uint2*)(qb + (size_t)r * D + d0);
    float4 qv;
    qv.x = __uint_as_float(qw.x << 16);
    qv.y = __uint_as_float(qw.x & 0xFFFF0000u);
    qv.z = __uint_as_float(qw.y << 16);
    qv.w = __uint_as_float(qw.y & 0xFFFF0000u);
    int cnt = min(deg[r], MAXDEG);
    const int* row = eid + (size_t)r * MAXDEG;
    float l = 0.f, a0 = 0.f, a1 = 0.f, a2 = 0.f, a3 = 0.f;
    for (int base = 0; base < cnt; base += 8) {
        int eiA = base + slot, eiB = base + 4 + slot;
        bool vA = eiA < cnt, vB = eiB < cnt;
        int sA = vA ? row[eiA] : 0;
        int sB = vB ? row[eiB] : 0;
        uint4 wA = *(const uint4*)(kvb + (size_t)sA * D + d0);
        uint4 wB = *(const uint4*)(kvb + (size_t)sB * D + d0);
        {
            float k0 = __uint_as_float(wA.x << 16), v0 = __uint_as_float(wA.x & 0xFFFF0000u);
            float k1 = __uint_as_float(wA.y << 16), v1 = __uint_as_float(wA.y & 0xFFFF0000u);
            float k2 = __uint_as_float(wA.z << 16), v2 = __uint_as_float(wA.z & 0xFFFF0000u);
            float k3 = __uint_as_float(wA.w << 16), v3 = __uint_as_float(wA.w & 0xFFFF0000u);
            float p = qv.x * k0 + qv.y * k1 + qv.z * k2 + qv.w * k3;
            p += __shfl_xor(p, 1, 64);
            p += __shfl_xor(p, 2, 64);
            p += __shfl_xor(p, 4, 64);
            float e = vA ? exp2f(p) : 0.f;
            l += e;
            a0 += e * v0; a1 += e * v1; a2 += e * v2; a3 += e * v3;
        }
        {
            float k0 = __uint_as_float(wB.x << 16), v0 = __uint_as_float(wB.x & 0xFFFF0000u);
            float k1 = __uint_as_float(wB.y << 16), v1 = __uint_as_float(wB.y & 0xFFFF0000u);
            float k2 = __uint_as_float(wB.z << 16), v2 = __uint_as_float(wB.z & 0xFFFF0000u);
            float k3 = __uint_as_float(wB.w << 16), v3 = __uint_as_float(wB.w & 0xFFFF0000u);
            float p = qv.x * k0 + qv.y * k1 + qv.z * k2 + qv.w * k3;
            p += __shfl_xor(p, 1, 64);
            p += __shfl_xor(p, 2, 64);
            p += __shfl_xor(p, 4, 64);
            float e = vB ? exp2f(p) : 0.f;
            l += e;
            a0 += e * v0; a1 += e * v1; a2 += e * v2; a3 += e * v3;
        }
    }
    l  += __shfl_xor(l, 32, 64);
    a0 += __shfl_xor(a0, 32, 64);
    a1 += __shfl_xor(a1, 32, 64);
    a2 += __shfl_xor(a2, 32, 64);
    a3 += __shfl_xor(a3, 32, 64);
    if (wave == 1 && lane < 32) {
        sl[lane] = l;
        sa[lane][0] = a0; sa[lane][1] = a1; sa[lane][2] = a2; sa[lane][3] = a3;
    }
    __syncthreads();
    if (wave == 0 && lane < 32) {
        l += sl[lane];
        float inv = 1.f / (l + 1e-9f);
        bf16 o[4];
        o[0] = __float2bfloat16((a0 + sa[lane][0]) * inv);
        o[1] = __float2bfloat16((a1 + sa[lane][1]) * inv);
        o[2] = __float2bfloat16((a2 + sa[lane][2]) * inv);
        o[3] = __float2bfloat16((a3 + sa[lane][3]) * inv);
        *(uint2*)(out + (size_t)r * D + d0) = *(uint2*)o;
    }
}

// ---------------- decoder: out = relu(x@w1+b1)@w2+b2, wave per node ----------
__global__ void k_decode(const float* __restrict__ x,
                         const float* __restrict__ w1, const float* __restrict__ b1,
                         const float* __restrict__ w2, const float* __restrict__ b2,
                         float* __restrict__ out, int N) {
    int node = blockIdx.x * 4 + (threadIdx.x >> 6);
    int lane = threadIdx.x & 63;
    if (node >= N) return;
    float a0 = x[(size_t)node * D + lane], a1 = x[(size_t)node * D + lane + 64];
    float acc0 = a0 * w1[lane * 3 + 0] + a1 * w1[(lane + 64) * 3 + 0];
    float acc1 = a0 * w1[lane * 3 + 1] + a1 * w1[(lane + 64) * 3 + 1];
    float acc2 = a0 * w1[lane * 3 + 2] + a1 * w1[(lane + 64) * 3 + 2];
#pragma unroll
    for (int m = 32; m >= 1; m >>= 1) {
        acc0 += __shfl_xor(acc0, m, 64);
        acc1 += __shfl_xor(acc1, m, 64);
        acc2 += __shfl_xor(acc2, m, 64);
    }
    if (lane == 0) {
        float t0 = fmaxf(acc0 + b1[0], 0.f);
        float t1 = fmaxf(acc1 + b1[1], 0.f);
        float t2 = fmaxf(acc2 + b1[2], 0.f);
        for (int o = 0; o < 3; o++)
            out[(size_t)node * 3 + o] =
                t0 * w2[0 * 3 + o] + t1 * w2[1 * 3 + o] + t2 * w2[2 * 3 + o] + b2[o];
    }
}

extern "C" void kernel_launch(void* const* d_in, const int* in_sizes, int n_in,
                              void* d_out, int out_size, void* d_ws, size_t ws_size,
                              hipStream_t stream) {
    const float* feat    = (const float*)d_in[0];
    const int*   senders = (const int*)d_in[1];
    const int*   recv    = (const int*)d_in[2];
    const float* enc_w1  = (const float*)d_in[3];
    const float* enc_b1  = (const float*)d_in[4];
    const float* enc_w2  = (const float*)d_in[5];
    const float* enc_b2  = (const float*)d_in[6];
    const float* wq      = (const float*)d_in[7];
    const float* wk      = (const float*)d_in[8];
    const float* wv      = (const float*)d_in[9];
    const float* wo      = (const float*)d_in[10];
    const float* ln1_s   = (const float*)d_in[11];
    const float* ln1_b   = (const float*)d_in[12];
    const float* ffn_w1  = (const float*)d_in[13];
    const float* ffn_b1  = (const float*)d_in[14];
    const float* ffn_w2  = (const float*)d_in[15];
    const float* ffn_b2  = (const float*)d_in[16];
    const float* ln2_s   = (const float*)d_in[17];
    const float* ln2_b   = (const float*)d_in[18];
    const float* dec_w1  = (const float*)d_in[19];
    const float* dec_b1  = (const float*)d_in[20];
    const float* dec_w2  = (const float*)d_in[21];
    const float* dec_b2  = (const float*)d_in[22];

    int N = in_sizes[0] / DIN;
    int E = in_sizes[1];

    // workspace layout
    char* p = (char*)d_ws;
    float* x   = (float*)p;  p += (size_t)N * D * 4;        // residual fp32
    bf16*  qb  = (bf16*)p;   p += (size_t)N * D * 2;        // q bf16 (pre-scaled)
    bf16*  kvb = (bf16*)p;   p += (size_t)N * D * 2 * 2;    // (k,v) bf16 interleaved
    bf16*  hb  = (bf16*)p;   p += (size_t)N * D * 2;        // LN out / attn out bf16
    int* deg   = (int*)p;    p += (size_t)N * 4;
    int* eid   = (int*)p;    p += (size_t)N * MAXDEG * 4;
    bf16* wqkvT  = (bf16*)p; p += (size_t)4 * 3 * D * D * 2;
    bf16* woT    = (bf16*)p; p += (size_t)4 * D * D * 2;
    bf16* w1T    = (bf16*)p; p += (size_t)4 * D * DFF * 2;
    bf16* w2T    = (bf16*)p; p += (size_t)4 * DFF * D * 2;
    bf16* encw2T = (bf16*)p; p += (size_t)D * D * 2;

    int gm = (N + BM - 1) / BM;   // 782

    k_wt<<<dim3(256, 25), 256, 0, stream>>>(wq, wk, wv, wo, ffn_w1, ffn_w2, enc_w2,
                                            wqkvT, woT, w1T, w2T, encw2T);
    k_zero_int<<<(N + 255) / 256, 256, 0, stream>>>(deg, N);
    k_fill<<<(E + 255) / 256, 256, 0, stream>>>(recv, senders, deg, eid, E);
    k_enc1<<<(N + TN - 1) / TN, 128, 0, stream>>>(feat, enc_w1, enc_b1, hb, N);
    // x = hb @ enc_w2 + b2; hb = LN1_0(x)
    k_gemm<5><<<dim3(gm, 1), 256, 0, stream>>>(hb, encw2T, enc_b2,
                                               ln1_s, ln1_b, x, nullptr, hb, N, D);

    for (int l = 0; l < 4; l++) {
        // qb/kvb from hb
        k_gemm<0><<<dim3(gm, 3), 256, 0, stream>>>(hb, wqkvT + (size_t)l * 3 * D * D,
                                                   nullptr, nullptr, nullptr,
                                                   nullptr, qb, kvb, N, D);
        k_attn<<<N, 128, 0, stream>>>(qb, (const uint*)kvb, deg, eid, hb, N);
        // x += hb @ wo; hb = LN2(x)
        k_gemm<2><<<dim3(gm, 1), 256, 0, stream>>>(hb, woT + (size_t)l * D * D,
                                                   nullptr, ln2_s + l * D, ln2_b + l * D,
                                                   x, nullptr, hb, N, D);
        // x += relu(hb@w1+b1)@w2 + b2; [LN1_{l+1} -> hb]
        if (l < 3)
            k_ffn<true><<<gm, 256, 0, stream>>>(hb, w1T + (size_t)l * D * DFF,
                                                ffn_b1 + l * DFF,
                                                w2T + (size_t)l * DFF * D, ffn_b2 + l * D,
                                                ln1_s + (l + 1) * D, ln1_b + (l + 1) * D,
                                                x, hb, N);
        else
            k_ffn<false><<<gm, 256, 0, stream>>>(hb, w1T + (size_t)l * D * DFF,
                                                 ffn_b1 + l * DFF,
                                                 w2T + (size_t)l * DFF * D, ffn_b2 + l * D,
                                                 nullptr, nullptr, x, nullptr, N);
    }
    k_decode<<<(N + 3) / 4, 256, 0, stream>>>(x, dec_w1, dec_b1, dec_w2, dec_b2,
                                              (float*)d_out, N);
}

// Round 12
// 769.255 us; speedup vs baseline: 1.6983x; 1.0183x over previous
//
#include <hip/hip_runtime.h>
#include <hip/hip_bf16.h>
#include <math.h>

#define D     128
#define NHEAD 4
#define DH    32
#define DFF   512
#define DIN   16
#define MAXDEG 64
#define TN    16

typedef __attribute__((ext_vector_type(8))) short bf16x8;
typedef __attribute__((ext_vector_type(4))) float f32x4;
typedef __hip_bfloat16 bf16;

// 1/sqrt(32) * log2(e): q pre-scaled so attn weight = exp2(q.k)
#define QSCALE_L2E 0.2550348838f

// LDS row pad 132 bf16 (66 dwords = 2 mod 32): fragment reads conflict-free.
// r10 NOTE: register-prefetch of weight tiles spills (WRITE 25->104MB) — don't.
// r11 NOTE: bank conflicts are NOT the k_ffn bottleneck (1.7M = ~2.8us);
//           k_ffn is occupancy/barrier-latency bound at 2 blocks/CU.
#define AP 132

// ---------------- CSR build ----------------
__global__ void k_zero_int(int* p, int n) {
    int i = blockIdx.x * blockDim.x + threadIdx.x;
    if (i < n) p[i] = 0;
}

__global__ void k_fill(const int* __restrict__ recv, const int* __restrict__ senders,
                       int* __restrict__ deg, int* __restrict__ eid, int E) {
    int e = blockIdx.x * blockDim.x + threadIdx.x;
    if (e >= E) return;
    int r = recv[e];
    int pos = atomicAdd(&deg[r], 1);
    if (pos < MAXDEG) eid[r * MAXDEG + pos] = senders[e];
}

// ---------------- weight transpose + bf16 convert (one launch, 25 regions) ----
__global__ void k_wt(const float* __restrict__ wq, const float* __restrict__ wk,
                     const float* __restrict__ wv, const float* __restrict__ wo,
                     const float* __restrict__ w1, const float* __restrict__ w2,
                     const float* __restrict__ encw2,
                     bf16* __restrict__ wqkvT, bf16* __restrict__ woT,
                     bf16* __restrict__ w1T, bf16* __restrict__ w2T,
                     bf16* __restrict__ encw2T) {
    int r = blockIdx.y;
    const float* src; bf16* dst; int K, Nout;
    if (r < 12) {
        int l = r / 3, sel = r % 3;
        src = (sel == 0 ? wq : sel == 1 ? wk : wv) + (size_t)l * D * D;
        dst = wqkvT + (size_t)l * 3 * D * D + (size_t)sel * D * D;
        K = D; Nout = D;
    } else if (r < 16) {
        int l = r - 12;
        src = wo + (size_t)l * D * D; dst = woT + (size_t)l * D * D; K = D; Nout = D;
    } else if (r < 20) {
        int l = r - 16;
        src = w1 + (size_t)l * D * DFF; dst = w1T + (size_t)l * D * DFF; K = D; Nout = DFF;
    } else if (r < 24) {
        int l = r - 20;
        src = w2 + (size_t)l * DFF * D; dst = w2T + (size_t)l * DFF * D; K = DFF; Nout = D;
    } else {
        src = encw2; dst = encw2T; K = D; Nout = D;
    }
    int total = K * Nout;
    int i = blockIdx.x * blockDim.x + threadIdx.x;
    if (i >= total) return;
    int k = i / Nout, j = i % Nout;
    dst[(size_t)j * K + k] = __float2bfloat16(src[i]);
}

// ---------------- fused QKV: one block per 64 rows, A staged ONCE ----------
// 782 blocks x 50.7KB LDS -> 3 blocks/CU -> 768 resident = 1.02 rounds.
// y-loop stages wq/wk/wv (128x128 each) into Wsm and runs 32 MFMA/wave.
__global__ __launch_bounds__(256) void k_qkv(
        const bf16* __restrict__ hb, const bf16* __restrict__ wqkvT,
        bf16* __restrict__ qb, bf16* __restrict__ kvb, int N) {
    __shared__ alignas(16) bf16 Asm[64][AP];     // 16.9 KB
    __shared__ alignas(16) bf16 Wsm[128][AP];    // 33.8 KB
    int m0 = blockIdx.x * 64;
    int t = threadIdx.x;
    int wave = t >> 6, lane = t & 63;
    int quad = lane >> 4, l16 = lane & 15;
    int wm = wave * 16;

    // stage A: 64 x 128 = 1024 x 16B, 4/thread
#pragma unroll
    for (int it = 0; it < 4; it++) {
        int ci = it * 256 + t;
        int rr = ci >> 4, cc = (ci & 15) * 8;
        int gr = m0 + rr;
        uint4 val = make_uint4(0u, 0u, 0u, 0u);
        if (gr < N) val = *(const uint4*)(hb + (size_t)gr * D + cc);
        *(uint4*)&Asm[rr][cc] = val;
    }
    __syncthreads();

    for (int y = 0; y < 3; y++) {
        const bf16* W = wqkvT + (size_t)y * D * D;
        // stage W: 128 x 128 = 2048 x 16B, 8/thread
#pragma unroll
        for (int it = 0; it < 8; it++) {
            int ci = it * 256 + t;
            int rr = ci >> 4, cc = (ci & 15) * 8;
            *(uint4*)&Wsm[rr][cc] = *(const uint4*)(W + (size_t)rr * D + cc);
        }
        __syncthreads();

        f32x4 acc[8];
#pragma unroll
        for (int j = 0; j < 8; j++) acc[j] = (f32x4){0.f, 0.f, 0.f, 0.f};
#pragma unroll
        for (int ks = 0; ks < 128; ks += 32) {
            bf16x8 af = *(const bf16x8*)&Asm[wm + l16][ks + quad * 8];
#pragma unroll
            for (int j = 0; j < 8; j++) {
                bf16x8 bfr = *(const bf16x8*)&Wsm[j * 16 + l16][ks + quad * 8];
                acc[j] = __builtin_amdgcn_mfma_f32_16x16x32_bf16(af, bfr, acc[j], 0, 0, 0);
            }
        }
        // epilogue: C[row = quad*4+reg][col = l16] per 16x16 tile
        int rowb = m0 + wm + quad * 4;
#pragma unroll
        for (int j = 0; j < 8; j++) {
            int col = j * 16 + l16;
#pragma unroll
            for (int r = 0; r < 4; r++) {
                int gr = rowb + r;
                if (gr >= N) continue;
                float val = acc[j][r];
                if (y == 0) qb[(size_t)gr * D + col] = __float2bfloat16(val * QSCALE_L2E);
                else kvb[((size_t)gr * D + col) * 2 + (y - 1)] = __float2bfloat16(val);
            }
        }
        if (y < 2) __syncthreads();   // protect Wsm before restage
    }
}

// ---------------- bf16 MFMA GEMM, BM=64 x BN=128, fused epilogues ----------
// OPs:
//   2 RES_LN : x += val; LN(x) -> outB          (wo + ln2)
//   5 BIAS_LN: x = val + bias; LN(x) -> outB    (encode + ln1 of layer 0)
#define BM 64
#define BK 64
#define BKP (BK + 8)

template<int OP>
__global__ __launch_bounds__(256) void k_gemm(
        const bf16* A, const bf16* __restrict__ Bt,
        const float* __restrict__ bias,
        const float* __restrict__ lns, const float* __restrict__ lnb,
        float* x, bf16* outB, int N, int K) {
    __shared__ alignas(16) bf16 Asm[BM][BKP];
    __shared__ alignas(16) bf16 Bsm[128][BKP];
    int m0 = blockIdx.x * BM;
    int y = blockIdx.y;
    const bf16* Bt_ = Bt + (size_t)y * 128 * K;
    int t = threadIdx.x;
    int wave = t >> 6, lane = t & 63;
    int quad = lane >> 4, l16 = lane & 15;
    int wm = wave * 16;

    f32x4 acc[8];
#pragma unroll
    for (int j = 0; j < 8; j++) acc[j] = (f32x4){0.f, 0.f, 0.f, 0.f};

    for (int k0 = 0; k0 < K; k0 += BK) {
#pragma unroll
        for (int it = 0; it < 2; it++) {
            int ci = it * 256 + t;
            int rr = ci >> 3, cc = (ci & 7) * 8;
            int gr = m0 + rr;
            uint4 val = make_uint4(0u, 0u, 0u, 0u);
            if (gr < N) val = *(const uint4*)(A + (size_t)gr * K + k0 + cc);
            *(uint4*)&Asm[rr][cc] = val;
        }
#pragma unroll
        for (int it = 0; it < 4; it++) {
            int ci = it * 256 + t;
            int rr = ci >> 3, cc = (ci & 7) * 8;
            *(uint4*)&Bsm[rr][cc] = *(const uint4*)(Bt_ + (size_t)rr * K + k0 + cc);
        }
        __syncthreads();
#pragma unroll
        for (int ks = 0; ks < BK; ks += 32) {
            bf16x8 af = *(const bf16x8*)&Asm[wm + l16][ks + quad * 8];
#pragma unroll
            for (int j = 0; j < 8; j++) {
                bf16x8 bfr = *(const bf16x8*)&Bsm[j * 16 + l16][ks + quad * 8];
                acc[j] = __builtin_amdgcn_mfma_f32_16x16x32_bf16(af, bfr, acc[j], 0, 0, 0);
            }
        }
        __syncthreads();
    }

    // ---- epilogue: residual/bias combine + LN ----
    int rowb = m0 + wm + quad * 4;
    {
        float bv[8];
        if (OP == 5) {
#pragma unroll
            for (int j = 0; j < 8; j++) bv[j] = bias[j * 16 + l16];
        }
#pragma unroll
        for (int j = 0; j < 8; j++) {
            int col = j * 16 + l16;
#pragma unroll
            for (int r = 0; r < 4; r++) {
                int gr = rowb + r;
                if (gr >= N) continue;
                float val = acc[j][r];
                if (OP == 5) val += bv[j];
                if (OP == 2) val += x[(size_t)gr * D + col];
                acc[j][r] = val;
            }
        }
        float lsv[8], lbv[8];
#pragma unroll
        for (int j = 0; j < 8; j++) {
            lsv[j] = lns[j * 16 + l16];
            lbv[j] = lnb[j * 16 + l16];
        }
#pragma unroll
        for (int r = 0; r < 4; r++) {
            float s1 = 0.f, s2 = 0.f;
#pragma unroll
            for (int j = 0; j < 8; j++) {
                float v = acc[j][r];
                s1 += v; s2 += v * v;
            }
            s1 += __shfl_xor(s1, 1, 64);  s2 += __shfl_xor(s2, 1, 64);
            s1 += __shfl_xor(s1, 2, 64);  s2 += __shfl_xor(s2, 2, 64);
            s1 += __shfl_xor(s1, 4, 64);  s2 += __shfl_xor(s2, 4, 64);
            s1 += __shfl_xor(s1, 8, 64);  s2 += __shfl_xor(s2, 8, 64);
            float mu = s1 * (1.f / 128.f);
            float var = s2 * (1.f / 128.f) - mu * mu;
            float rinv = rsqrtf(fmaxf(var, 0.f) + 1e-5f);
            int gr = rowb + r;
            if (gr >= N) continue;
#pragma unroll
            for (int j = 0; j < 8; j++) {
                int col = j * 16 + l16;
                float v = acc[j][r];
                x[(size_t)gr * D + col] = v;
                outB[(size_t)gr * D + col] =
                    __float2bfloat16((v - mu) * rinv * lsv[j] + lbv[j]);
            }
        }
    }
}

// ---------------- fused FFN: x += relu(hb@w1+b1)@w2 + b2 [; LN -> hb] --------
// r8 structure (LDS-staged weight chunks) + AP=132 pads.
template<bool DOLN>
__global__ __launch_bounds__(256) void k_ffn(
        const bf16* hb, const bf16* __restrict__ w1T, const float* __restrict__ b1,
        const bf16* __restrict__ w2T, const float* __restrict__ b2,
        const float* __restrict__ lns, const float* __restrict__ lnb,
        float* x, bf16* outB, int N) {
    __shared__ alignas(16) bf16 Asm[64][AP];     // 16.9 KB
    __shared__ alignas(16) bf16 Wsm[128][AP];    // 33.8 KB (W1c / W2c)
    __shared__ alignas(16) bf16 Hsm[64][AP];     // 16.9 KB
    int m0 = blockIdx.x * 64;
    int t = threadIdx.x;
    int wave = t >> 6, lane = t & 63;
    int quad = lane >> 4, l16 = lane & 15;
    int wm = wave * 16;

#pragma unroll
    for (int it = 0; it < 4; it++) {
        int ci = it * 256 + t;
        int rr = ci >> 4, cc = (ci & 15) * 8;
        int gr = m0 + rr;
        uint4 val = make_uint4(0u, 0u, 0u, 0u);
        if (gr < N) val = *(const uint4*)(hb + (size_t)gr * D + cc);
        *(uint4*)&Asm[rr][cc] = val;
    }
#pragma unroll
    for (int it = 0; it < 8; it++) {
        int ci = it * 256 + t;
        int rr = ci >> 4, cc = (ci & 15) * 8;
        *(uint4*)&Wsm[rr][cc] = *(const uint4*)(w1T + (size_t)rr * D + cc);
    }
    __syncthreads();

    f32x4 acc2[8];
#pragma unroll
    for (int j = 0; j < 8; j++) acc2[j] = (f32x4){0.f, 0.f, 0.f, 0.f};

    for (int c = 0; c < 4; c++) {
        f32x4 accP[8];
#pragma unroll
        for (int j = 0; j < 8; j++) accP[j] = (f32x4){0.f, 0.f, 0.f, 0.f};
#pragma unroll
        for (int ks = 0; ks < 128; ks += 32) {
            bf16x8 af = *(const bf16x8*)&Asm[wm + l16][ks + quad * 8];
#pragma unroll
            for (int j = 0; j < 8; j++) {
                bf16x8 bfr = *(const bf16x8*)&Wsm[j * 16 + l16][ks + quad * 8];
                accP[j] = __builtin_amdgcn_mfma_f32_16x16x32_bf16(af, bfr, accP[j], 0, 0, 0);
            }
        }
        __syncthreads();
#pragma unroll
        for (int it = 0; it < 8; it++) {
            int ci = it * 256 + t;
            int rr = ci >> 4, cc = (ci & 15) * 8;
            *(uint4*)&Wsm[rr][cc] = *(const uint4*)(w2T + (size_t)rr * DFF + c * 128 + cc);
        }
        {
            float bv[8];
#pragma unroll
            for (int j = 0; j < 8; j++) bv[j] = b1[c * 128 + j * 16 + l16];
            int rw = wm + quad * 4;
#pragma unroll
            for (int j = 0; j < 8; j++) {
                int col = j * 16 + l16;
#pragma unroll
                for (int r = 0; r < 4; r++)
                    Hsm[rw + r][col] = __float2bfloat16(fmaxf(accP[j][r] + bv[j], 0.f));
            }
        }
        __syncthreads();
#pragma unroll
        for (int ks = 0; ks < 128; ks += 32) {
            bf16x8 af = *(const bf16x8*)&Hsm[wm + l16][ks + quad * 8];
#pragma unroll
            for (int j = 0; j < 8; j++) {
                bf16x8 bfr = *(const bf16x8*)&Wsm[j * 16 + l16][ks + quad * 8];
                acc2[j] = __builtin_amdgcn_mfma_f32_16x16x32_bf16(af, bfr, acc2[j], 0, 0, 0);
            }
        }
        if (c < 3) {
            __syncthreads();
#pragma unroll
            for (int it = 0; it < 8; it++) {
                int ci = it * 256 + t;
                int rr = ci >> 4, cc = (ci & 15) * 8;
                *(uint4*)&Wsm[rr][cc] =
                    *(const uint4*)(w1T + (size_t)((c + 1) * 128 + rr) * D + cc);
            }
            __syncthreads();
        }
    }

    int rowb = m0 + wm + quad * 4;
    float bv[8];
#pragma unroll
    for (int j = 0; j < 8; j++) bv[j] = b2[j * 16 + l16];
#pragma unroll
    for (int j = 0; j < 8; j++) {
        int col = j * 16 + l16;
#pragma unroll
        for (int r = 0; r < 4; r++) {
            int gr = rowb + r;
            if (gr >= N) continue;
            acc2[j][r] += bv[j] + x[(size_t)gr * D + col];
        }
    }
    if (!DOLN) {
#pragma unroll
        for (int j = 0; j < 8; j++) {
            int col = j * 16 + l16;
#pragma unroll
            for (int r = 0; r < 4; r++) {
                int gr = rowb + r;
                if (gr < N) x[(size_t)gr * D + col] = acc2[j][r];
            }
        }
        return;
    }
    float lsv[8], lbv[8];
#pragma unroll
    for (int j = 0; j < 8; j++) {
        lsv[j] = lns[j * 16 + l16];
        lbv[j] = lnb[j * 16 + l16];
    }
#pragma unroll
    for (int r = 0; r < 4; r++) {
        float s1 = 0.f, s2 = 0.f;
#pragma unroll
        for (int j = 0; j < 8; j++) {
            float v = acc2[j][r];
            s1 += v; s2 += v * v;
        }
        s1 += __shfl_xor(s1, 1, 64);  s2 += __shfl_xor(s2, 1, 64);
        s1 += __shfl_xor(s1, 2, 64);  s2 += __shfl_xor(s2, 2, 64);
        s1 += __shfl_xor(s1, 4, 64);  s2 += __shfl_xor(s2, 4, 64);
        s1 += __shfl_xor(s1, 8, 64);  s2 += __shfl_xor(s2, 8, 64);
        float mu = s1 * (1.f / 128.f);
        float var = s2 * (1.f / 128.f) - mu * mu;
        float rinv = rsqrtf(fmaxf(var, 0.f) + 1e-5f);
        int gr = rowb + r;
        if (gr >= N) continue;
#pragma unroll
        for (int j = 0; j < 8; j++) {
            int col = j * 16 + l16;
            float v = acc2[j][r];
            x[(size_t)gr * D + col] = v;
            outB[(size_t)gr * D + col] = __float2bfloat16((v - mu) * rinv * lsv[j] + lbv[j]);
        }
    }
}

// ---------------- encoder stage 1: hb = bf16(relu(f@w1+b1)) ----------------
__global__ void k_enc1(const float* __restrict__ feat,
                       const float* __restrict__ w1, const float* __restrict__ b1,
                       bf16* __restrict__ hb, int N) {
    __shared__ float fsh[TN][DIN];
    int n0 = blockIdx.x * TN;
    int j = threadIdx.x;            // 0..127
    int nvalid = min(TN, N - n0);
    for (int idx = j; idx < TN * DIN; idx += 128) {
        int n = idx / DIN, i = idx % DIN;
        fsh[n][i] = (n < nvalid) ? feat[(n0 + n) * DIN + i] : 0.f;
    }
    __syncthreads();
    float bb = b1[j];
#pragma unroll
    for (int n = 0; n < TN; n++) {
        float a = bb;
#pragma unroll
        for (int i = 0; i < DIN; i++) a += fsh[n][i] * w1[i * D + j];
        if (n < nvalid) hb[(size_t)(n0 + n) * D + j] = __float2bfloat16(fmaxf(a, 0.f));
    }
}

// ---------------- fused per-receiver softmax attention (8-lane edge-head) ----
__global__ __launch_bounds__(128) void k_attn(
        const bf16* __restrict__ qb, const uint* __restrict__ kvb,
        const int* __restrict__ deg, const int* __restrict__ eid,
        bf16* __restrict__ out, int N) {
    __shared__ float sl[32], sa[32][4];
    int r = blockIdx.x;
    int t = threadIdx.x;
    int wave = t >> 6, lane = t & 63;
    int g = lane & 7;                    // dim group
    int h = (lane >> 3) & 3;             // head
    int slot = wave * 2 + (lane >> 5);   // edge slot 0..3
    int d0 = h * 32 + g * 4;
    uint2 qw = *(const uint2*)(qb + (size_t)r * D + d0);
    float4 qv;
    qv.x = __uint_as_float(qw.x << 16);
    qv.y = __uint_as_float(qw.x & 0xFFFF0000u);
    qv.z = __uint_as_float(qw.y << 16);
    qv.w = __uint_as_float(qw.y & 0xFFFF0000u);
    int cnt = min(deg[r], MAXDEG);
    const int* row = eid + (size_t)r * MAXDEG;
    float l = 0.f, a0 = 0.f, a1 = 0.f, a2 = 0.f, a3 = 0.f;
    for (int base = 0; base < cnt; base += 8) {
        int eiA = base + slot, eiB = base + 4 + slot;
        bool vA = eiA < cnt, vB = eiB < cnt;
        int sA = vA ? row[eiA] : 0;
        int sB = vB ? row[eiB] : 0;
        uint4 wA = *(const uint4*)(kvb + (size_t)sA * D + d0);
        uint4 wB = *(const uint4*)(kvb + (size_t)sB * D + d0);
        {
            float k0 = __uint_as_float(wA.x << 16), v0 = __uint_as_float(wA.x & 0xFFFF0000u);
            float k1 = __uint_as_float(wA.y << 16), v1 = __uint_as_float(wA.y & 0xFFFF0000u);
            float k2 = __uint_as_float(wA.z << 16), v2 = __uint_as_float(wA.z & 0xFFFF0000u);
            float k3 = __uint_as_float(wA.w << 16), v3 = __uint_as_float(wA.w & 0xFFFF0000u);
            float p = qv.x * k0 + qv.y * k1 + qv.z * k2 + qv.w * k3;
            p += __shfl_xor(p, 1, 64);
            p += __shfl_xor(p, 2, 64);
            p += __shfl_xor(p, 4, 64);
            float e = vA ? exp2f(p) : 0.f;
            l += e;
            a0 += e * v0; a1 += e * v1; a2 += e * v2; a3 += e * v3;
        }
        {
            float k0 = __uint_as_float(wB.x << 16), v0 = __uint_as_float(wB.x & 0xFFFF0000u);
            float k1 = __uint_as_float(wB.y << 16), v1 = __uint_as_float(wB.y & 0xFFFF0000u);
            float k2 = __uint_as_float(wB.z << 16), v2 = __uint_as_float(wB.z & 0xFFFF0000u);
            float k3 = __uint_as_float(wB.w << 16), v3 = __uint_as_float(wB.w & 0xFFFF0000u);
            float p = qv.x * k0 + qv.y * k1 + qv.z * k2 + qv.w * k3;
            p += __shfl_xor(p, 1, 64);
            p += __shfl_xor(p, 2, 64);
            p += __shfl_xor(p, 4, 64);
            float e = vB ? exp2f(p) : 0.f;
            l += e;
            a0 += e * v0; a1 += e * v1; a2 += e * v2; a3 += e * v3;
        }
    }
    l  += __shfl_xor(l, 32, 64);
    a0 += __shfl_xor(a0, 32, 64);
    a1 += __shfl_xor(a1, 32, 64);
    a2 += __shfl_xor(a2, 32, 64);
    a3 += __shfl_xor(a3, 32, 64);
    if (wave == 1 && lane < 32) {
        sl[lane] = l;
        sa[lane][0] = a0; sa[lane][1] = a1; sa[lane][2] = a2; sa[lane][3] = a3;
    }
    __syncthreads();
    if (wave == 0 && lane < 32) {
        l += sl[lane];
        float inv = 1.f / (l + 1e-9f);
        bf16 o[4];
        o[0] = __float2bfloat16((a0 + sa[lane][0]) * inv);
        o[1] = __float2bfloat16((a1 + sa[lane][1]) * inv);
        o[2] = __float2bfloat16((a2 + sa[lane][2]) * inv);
        o[3] = __float2bfloat16((a3 + sa[lane][3]) * inv);
        *(uint2*)(out + (size_t)r * D + d0) = *(uint2*)o;
    }
}

// ---------------- decoder: out = relu(x@w1+b1)@w2+b2, wave per node ----------
__global__ void k_decode(const float* __restrict__ x,
                         const float* __restrict__ w1, const float* __restrict__ b1,
                         const float* __restrict__ w2, const float* __restrict__ b2,
                         float* __restrict__ out, int N) {
    int node = blockIdx.x * 4 + (threadIdx.x >> 6);
    int lane = threadIdx.x & 63;
    if (node >= N) return;
    float a0 = x[(size_t)node * D + lane], a1 = x[(size_t)node * D + lane + 64];
    float acc0 = a0 * w1[lane * 3 + 0] + a1 * w1[(lane + 64) * 3 + 0];
    float acc1 = a0 * w1[lane * 3 + 1] + a1 * w1[(lane + 64) * 3 + 1];
    float acc2 = a0 * w1[lane * 3 + 2] + a1 * w1[(lane + 64) * 3 + 2];
#pragma unroll
    for (int m = 32; m >= 1; m >>= 1) {
        acc0 += __shfl_xor(acc0, m, 64);
        acc1 += __shfl_xor(acc1, m, 64);
        acc2 += __shfl_xor(acc2, m, 64);
    }
    if (lane == 0) {
        float t0 = fmaxf(acc0 + b1[0], 0.f);
        float t1 = fmaxf(acc1 + b1[1], 0.f);
        float t2 = fmaxf(acc2 + b1[2], 0.f);
        for (int o = 0; o < 3; o++)
            out[(size_t)node * 3 + o] =
                t0 * w2[0 * 3 + o] + t1 * w2[1 * 3 + o] + t2 * w2[2 * 3 + o] + b2[o];
    }
}

extern "C" void kernel_launch(void* const* d_in, const int* in_sizes, int n_in,
                              void* d_out, int out_size, void* d_ws, size_t ws_size,
                              hipStream_t stream) {
    const float* feat    = (const float*)d_in[0];
    const int*   senders = (const int*)d_in[1];
    const int*   recv    = (const int*)d_in[2];
    const float* enc_w1  = (const float*)d_in[3];
    const float* enc_b1  = (const float*)d_in[4];
    const float* enc_w2  = (const float*)d_in[5];
    const float* enc_b2  = (const float*)d_in[6];
    const float* wq      = (const float*)d_in[7];
    const float* wk      = (const float*)d_in[8];
    const float* wv      = (const float*)d_in[9];
    const float* wo      = (const float*)d_in[10];
    const float* ln1_s   = (const float*)d_in[11];
    const float* ln1_b   = (const float*)d_in[12];
    const float* ffn_w1  = (const float*)d_in[13];
    const float* ffn_b1  = (const float*)d_in[14];
    const float* ffn_w2  = (const float*)d_in[15];
    const float* ffn_b2  = (const float*)d_in[16];
    const float* ln2_s   = (const float*)d_in[17];
    const float* ln2_b   = (const float*)d_in[18];
    const float* dec_w1  = (const float*)d_in[19];
    const float* dec_b1  = (const float*)d_in[20];
    const float* dec_w2  = (const float*)d_in[21];
    const float* dec_b2  = (const float*)d_in[22];

    int N = in_sizes[0] / DIN;
    int E = in_sizes[1];

    // workspace layout
    char* p = (char*)d_ws;
    float* x   = (float*)p;  p += (size_t)N * D * 4;        // residual fp32
    bf16*  qb  = (bf16*)p;   p += (size_t)N * D * 2;        // q bf16 (pre-scaled)
    bf16*  kvb = (bf16*)p;   p += (size_t)N * D * 2 * 2;    // (k,v) bf16 interleaved
    bf16*  hb  = (bf16*)p;   p += (size_t)N * D * 2;        // LN out / attn out bf16
    int* deg   = (int*)p;    p += (size_t)N * 4;
    int* eid   = (int*)p;    p += (size_t)N * MAXDEG * 4;
    bf16* wqkvT  = (bf16*)p; p += (size_t)4 * 3 * D * D * 2;
    bf16* woT    = (bf16*)p; p += (size_t)4 * D * D * 2;
    bf16* w1T    = (bf16*)p; p += (size_t)4 * D * DFF * 2;
    bf16* w2T    = (bf16*)p; p += (size_t)4 * DFF * D * 2;
    bf16* encw2T = (bf16*)p; p += (size_t)D * D * 2;

    int gm = (N + BM - 1) / BM;   // 782

    k_wt<<<dim3(256, 25), 256, 0, stream>>>(wq, wk, wv, wo, ffn_w1, ffn_w2, enc_w2,
                                            wqkvT, woT, w1T, w2T, encw2T);
    k_zero_int<<<(N + 255) / 256, 256, 0, stream>>>(deg, N);
    k_fill<<<(E + 255) / 256, 256, 0, stream>>>(recv, senders, deg, eid, E);
    k_enc1<<<(N + TN - 1) / TN, 128, 0, stream>>>(feat, enc_w1, enc_b1, hb, N);
    // x = hb @ enc_w2 + b2; hb = LN1_0(x)
    k_gemm<5><<<dim3(gm, 1), 256, 0, stream>>>(hb, encw2T, enc_b2,
                                               ln1_s, ln1_b, x, hb, N, D);

    for (int l = 0; l < 4; l++) {
        // qb/kvb from hb (fused q/k/v, A staged once, 3 blocks/CU)
        k_qkv<<<gm, 256, 0, stream>>>(hb, wqkvT + (size_t)l * 3 * D * D, qb, kvb, N);
        k_attn<<<N, 128, 0, stream>>>(qb, (const uint*)kvb, deg, eid, hb, N);
        // x += hb @ wo; hb = LN2(x)
        k_gemm<2><<<dim3(gm, 1), 256, 0, stream>>>(hb, woT + (size_t)l * D * D,
                                                   nullptr, ln2_s + l * D, ln2_b + l * D,
                                                   x, hb, N, D);
        // x += relu(hb@w1+b1)@w2 + b2; [LN1_{l+1} -> hb]
        if (l < 3)
            k_ffn<true><<<gm, 256, 0, stream>>>(hb, w1T + (size_t)l * D * DFF,
                                                ffn_b1 + l * DFF,
                                                w2T + (size_t)l * DFF * D, ffn_b2 + l * D,
                                                ln1_s + (l + 1) * D, ln1_b + (l + 1) * D,
                                                x, hb, N);
        else
            k_ffn<false><<<gm, 256, 0, stream>>>(hb, w1T + (size_t)l * D * DFF,
                                                 ffn_b1 + l * DFF,
                                                 w2T + (size_t)l * DFF * D, ffn_b2 + l * D,
                                                 nullptr, nullptr, x, nullptr, N);
    }
    k_decode<<<(N + 3) / 4, 256, 0, stream>>>(x, dec_w1, dec_b1, dec_w2, dec_b2,
                                              (float*)d_out, N);
}

// Round 13
// 760.971 us; speedup vs baseline: 1.7168x; 1.0109x over previous
//
#include <hip/hip_runtime.h>
#include <hip/hip_bf16.h>
#include <math.h>

#define D     128
#define NHEAD 4
#define DH    32
#define DFF   512
#define DIN   16
#define MAXDEG 64
#define TN    16

typedef __attribute__((ext_vector_type(8))) short bf16x8;
typedef __attribute__((ext_vector_type(4))) float f32x4;
typedef __hip_bfloat16 bf16;

// 1/sqrt(32) * log2(e): q pre-scaled so attn weight = exp2(q.k)
#define QSCALE_L2E 0.2550348838f

// LDS row pad 132 bf16 (66 dwords = 2 mod 32): fragment reads 2-way (free),
// C-layout scalar writes conflict-free.
// r10: register-prefetch of weight tiles spills — don't.
// r13: A-fragments live in 16 VGPRs loaded straight from global (each wave
//      reads only its own 16 rows; frag = 16B contiguous) — no Asm in LDS.
#define AP 132
#define BM 64

// ---------------- CSR build ----------------
__global__ void k_zero_int(int* p, int n) {
    int i = blockIdx.x * blockDim.x + threadIdx.x;
    if (i < n) p[i] = 0;
}

__global__ void k_fill(const int* __restrict__ recv, const int* __restrict__ senders,
                       int* __restrict__ deg, int* __restrict__ eid, int E) {
    int e = blockIdx.x * blockDim.x + threadIdx.x;
    if (e >= E) return;
    int r = recv[e];
    int pos = atomicAdd(&deg[r], 1);
    if (pos < MAXDEG) eid[r * MAXDEG + pos] = senders[e];
}

// ---------------- weight transpose + bf16 convert (one launch, 25 regions) ----
__global__ void k_wt(const float* __restrict__ wq, const float* __restrict__ wk,
                     const float* __restrict__ wv, const float* __restrict__ wo,
                     const float* __restrict__ w1, const float* __restrict__ w2,
                     const float* __restrict__ encw2,
                     bf16* __restrict__ wqkvT, bf16* __restrict__ woT,
                     bf16* __restrict__ w1T, bf16* __restrict__ w2T,
                     bf16* __restrict__ encw2T) {
    int r = blockIdx.y;
    const float* src; bf16* dst; int K, Nout;
    if (r < 12) {
        int l = r / 3, sel = r % 3;
        src = (sel == 0 ? wq : sel == 1 ? wk : wv) + (size_t)l * D * D;
        dst = wqkvT + (size_t)l * 3 * D * D + (size_t)sel * D * D;
        K = D; Nout = D;
    } else if (r < 16) {
        int l = r - 12;
        src = wo + (size_t)l * D * D; dst = woT + (size_t)l * D * D; K = D; Nout = D;
    } else if (r < 20) {
        int l = r - 16;
        src = w1 + (size_t)l * D * DFF; dst = w1T + (size_t)l * D * DFF; K = D; Nout = DFF;
    } else if (r < 24) {
        int l = r - 20;
        src = w2 + (size_t)l * DFF * D; dst = w2T + (size_t)l * DFF * D; K = DFF; Nout = D;
    } else {
        src = encw2; dst = encw2T; K = D; Nout = D;
    }
    int total = K * Nout;
    int i = blockIdx.x * blockDim.x + threadIdx.x;
    if (i >= total) return;
    int k = i / Nout, j = i % Nout;
    dst[(size_t)j * K + k] = __float2bfloat16(src[i]);
}

// helper: load this wave's 4 A-fragments (16 rows x 128 cols) from global
__device__ __forceinline__ void load_afrag(const bf16* A, int arow, int quad,
                                           int N, bf16x8* afr) {
    const bf16* ab = A + (size_t)arow * D + quad * 8;
#pragma unroll
    for (int i = 0; i < 4; i++) {
        uint4 v = make_uint4(0u, 0u, 0u, 0u);
        if (arow < N) v = *(const uint4*)(ab + i * 32);
        afr[i] = *(bf16x8*)&v;
    }
}

// ---------------- bf16 MFMA GEMM, 64 rows x 128 cols, K=128, 1 barrier ------
// A-fragments in registers; only the weight tile (128x128) in LDS.
// OPs: 2 RES_LN (wo+ln2), 5 BIAS_LN (encode+ln1_0)
template<int OP>
__global__ __launch_bounds__(256) void k_gemm(
        const bf16* __restrict__ A, const bf16* __restrict__ Bt,
        const float* __restrict__ bias,
        const float* __restrict__ lns, const float* __restrict__ lnb,
        float* x, bf16* outB, int N) {
    __shared__ alignas(16) bf16 Wsm[128][AP];    // 33.8 KB -> 4 blocks/CU
    int m0 = blockIdx.x * BM;
    int t = threadIdx.x;
    int wave = t >> 6, lane = t & 63;
    int quad = lane >> 4, l16 = lane & 15;
    int wm = wave * 16;

    bf16x8 afr[4];
    load_afrag(A, m0 + wm + l16, quad, N, afr);
#pragma unroll
    for (int it = 0; it < 8; it++) {
        int ci = it * 256 + t;
        int rr = ci >> 4, cc = (ci & 15) * 8;
        *(uint4*)&Wsm[rr][cc] = *(const uint4*)(Bt + (size_t)rr * D + cc);
    }
    __syncthreads();

    f32x4 acc[8];
#pragma unroll
    for (int j = 0; j < 8; j++) acc[j] = (f32x4){0.f, 0.f, 0.f, 0.f};
#pragma unroll
    for (int i = 0; i < 4; i++) {
#pragma unroll
        for (int j = 0; j < 8; j++) {
            bf16x8 bfr = *(const bf16x8*)&Wsm[j * 16 + l16][i * 32 + quad * 8];
            acc[j] = __builtin_amdgcn_mfma_f32_16x16x32_bf16(afr[i], bfr, acc[j], 0, 0, 0);
        }
    }

    // epilogue: residual/bias combine + LN (C[row=quad*4+r][col=l16])
    int rowb = m0 + wm + quad * 4;
    float bv[8];
    if (OP == 5) {
#pragma unroll
        for (int j = 0; j < 8; j++) bv[j] = bias[j * 16 + l16];
    }
#pragma unroll
    for (int j = 0; j < 8; j++) {
        int col = j * 16 + l16;
#pragma unroll
        for (int r = 0; r < 4; r++) {
            int gr = rowb + r;
            if (gr >= N) continue;
            float val = acc[j][r];
            if (OP == 5) val += bv[j];
            if (OP == 2) val += x[(size_t)gr * D + col];
            acc[j][r] = val;
        }
    }
    float lsv[8], lbv[8];
#pragma unroll
    for (int j = 0; j < 8; j++) {
        lsv[j] = lns[j * 16 + l16];
        lbv[j] = lnb[j * 16 + l16];
    }
#pragma unroll
    for (int r = 0; r < 4; r++) {
        float s1 = 0.f, s2 = 0.f;
#pragma unroll
        for (int j = 0; j < 8; j++) {
            float v = acc[j][r];
            s1 += v; s2 += v * v;
        }
        s1 += __shfl_xor(s1, 1, 64);  s2 += __shfl_xor(s2, 1, 64);
        s1 += __shfl_xor(s1, 2, 64);  s2 += __shfl_xor(s2, 2, 64);
        s1 += __shfl_xor(s1, 4, 64);  s2 += __shfl_xor(s2, 4, 64);
        s1 += __shfl_xor(s1, 8, 64);  s2 += __shfl_xor(s2, 8, 64);
        float mu = s1 * (1.f / 128.f);
        float var = s2 * (1.f / 128.f) - mu * mu;
        float rinv = rsqrtf(fmaxf(var, 0.f) + 1e-5f);
        int gr = rowb + r;
        if (gr >= N) continue;
#pragma unroll
        for (int j = 0; j < 8; j++) {
            int col = j * 16 + l16;
            float v = acc[j][r];
            x[(size_t)gr * D + col] = v;
            outB[(size_t)gr * D + col] =
                __float2bfloat16((v - mu) * rinv * lsv[j] + lbv[j]);
        }
    }
}

// ---------------- fused QKV: A-frags in regs, weight tile in LDS ------------
__global__ __launch_bounds__(256) void k_qkv(
        const bf16* __restrict__ hb, const bf16* __restrict__ wqkvT,
        bf16* __restrict__ qb, bf16* __restrict__ kvb, int N) {
    __shared__ alignas(16) bf16 Wsm[128][AP];    // 33.8 KB -> 4 blocks/CU
    int m0 = blockIdx.x * BM;
    int t = threadIdx.x;
    int wave = t >> 6, lane = t & 63;
    int quad = lane >> 4, l16 = lane & 15;
    int wm = wave * 16;

    bf16x8 afr[4];
    load_afrag(hb, m0 + wm + l16, quad, N, afr);

    for (int y = 0; y < 3; y++) {
        const bf16* W = wqkvT + (size_t)y * D * D;
#pragma unroll
        for (int it = 0; it < 8; it++) {
            int ci = it * 256 + t;
            int rr = ci >> 4, cc = (ci & 15) * 8;
            *(uint4*)&Wsm[rr][cc] = *(const uint4*)(W + (size_t)rr * D + cc);
        }
        __syncthreads();

        f32x4 acc[8];
#pragma unroll
        for (int j = 0; j < 8; j++) acc[j] = (f32x4){0.f, 0.f, 0.f, 0.f};
#pragma unroll
        for (int i = 0; i < 4; i++) {
#pragma unroll
            for (int j = 0; j < 8; j++) {
                bf16x8 bfr = *(const bf16x8*)&Wsm[j * 16 + l16][i * 32 + quad * 8];
                acc[j] = __builtin_amdgcn_mfma_f32_16x16x32_bf16(afr[i], bfr, acc[j], 0, 0, 0);
            }
        }
        int rowb = m0 + wm + quad * 4;
#pragma unroll
        for (int j = 0; j < 8; j++) {
            int col = j * 16 + l16;
#pragma unroll
            for (int r = 0; r < 4; r++) {
                int gr = rowb + r;
                if (gr >= N) continue;
                float val = acc[j][r];
                if (y == 0) qb[(size_t)gr * D + col] = __float2bfloat16(val * QSCALE_L2E);
                else kvb[((size_t)gr * D + col) * 2 + (y - 1)] = __float2bfloat16(val);
            }
        }
        if (y < 2) __syncthreads();
    }
}

// ---------------- fused FFN: x += relu(hb@w1+b1)@w2 + b2 [; LN -> hb] --------
// A-frags in regs (GEMM1); Wsm (33.8K) + Hsm (16.9K) = 50.7 KB -> 3 blocks/CU.
template<bool DOLN>
__global__ __launch_bounds__(256) void k_ffn(
        const bf16* __restrict__ hb, const bf16* __restrict__ w1T,
        const float* __restrict__ b1,
        const bf16* __restrict__ w2T, const float* __restrict__ b2,
        const float* __restrict__ lns, const float* __restrict__ lnb,
        float* x, bf16* outB, int N) {
    __shared__ alignas(16) bf16 Wsm[128][AP];    // 33.8 KB (W1c / W2c)
    __shared__ alignas(16) bf16 Hsm[64][AP];     // 16.9 KB
    int m0 = blockIdx.x * 64;
    int t = threadIdx.x;
    int wave = t >> 6, lane = t & 63;
    int quad = lane >> 4, l16 = lane & 15;
    int wm = wave * 16;

    bf16x8 afr[4];
    load_afrag(hb, m0 + wm + l16, quad, N, afr);
#pragma unroll
    for (int it = 0; it < 8; it++) {
        int ci = it * 256 + t;
        int rr = ci >> 4, cc = (ci & 15) * 8;
        *(uint4*)&Wsm[rr][cc] = *(const uint4*)(w1T + (size_t)rr * D + cc);
    }
    __syncthreads();

    f32x4 acc2[8];
#pragma unroll
    for (int j = 0; j < 8; j++) acc2[j] = (f32x4){0.f, 0.f, 0.f, 0.f};

    for (int c = 0; c < 4; c++) {
        // P = A @ W1c (A from registers)
        f32x4 accP[8];
#pragma unroll
        for (int j = 0; j < 8; j++) accP[j] = (f32x4){0.f, 0.f, 0.f, 0.f};
#pragma unroll
        for (int i = 0; i < 4; i++) {
#pragma unroll
            for (int j = 0; j < 8; j++) {
                bf16x8 bfr = *(const bf16x8*)&Wsm[j * 16 + l16][i * 32 + quad * 8];
                accP[j] = __builtin_amdgcn_mfma_f32_16x16x32_bf16(afr[i], bfr, accP[j], 0, 0, 0);
            }
        }
        __syncthreads();   // Wsm(W1c) reads done; prev Hsm reads done
        // stage W2c + write Hsm = relu(P + b1)
#pragma unroll
        for (int it = 0; it < 8; it++) {
            int ci = it * 256 + t;
            int rr = ci >> 4, cc = (ci & 15) * 8;
            *(uint4*)&Wsm[rr][cc] = *(const uint4*)(w2T + (size_t)rr * DFF + c * 128 + cc);
        }
        {
            float bv[8];
#pragma unroll
            for (int j = 0; j < 8; j++) bv[j] = b1[c * 128 + j * 16 + l16];
            int rw = wm + quad * 4;
#pragma unroll
            for (int j = 0; j < 8; j++) {
                int col = j * 16 + l16;
#pragma unroll
                for (int r = 0; r < 4; r++)
                    Hsm[rw + r][col] = __float2bfloat16(fmaxf(accP[j][r] + bv[j], 0.f));
            }
        }
        __syncthreads();
        // acc2 += Hsm @ W2c
#pragma unroll
        for (int ks = 0; ks < 4; ks++) {
            bf16x8 af2 = *(const bf16x8*)&Hsm[wm + l16][ks * 32 + quad * 8];
#pragma unroll
            for (int j = 0; j < 8; j++) {
                bf16x8 bfr = *(const bf16x8*)&Wsm[j * 16 + l16][ks * 32 + quad * 8];
                acc2[j] = __builtin_amdgcn_mfma_f32_16x16x32_bf16(af2, bfr, acc2[j], 0, 0, 0);
            }
        }
        if (c < 3) {
            __syncthreads();   // Wsm(W2c) reads done
#pragma unroll
            for (int it = 0; it < 8; it++) {
                int ci = it * 256 + t;
                int rr = ci >> 4, cc = (ci & 15) * 8;
                *(uint4*)&Wsm[rr][cc] =
                    *(const uint4*)(w1T + (size_t)((c + 1) * 128 + rr) * D + cc);
            }
            __syncthreads();
        }
    }

    // epilogue: out = acc2 + b2 + x; [LN -> outB]; store x
    int rowb = m0 + wm + quad * 4;
    float bv[8];
#pragma unroll
    for (int j = 0; j < 8; j++) bv[j] = b2[j * 16 + l16];
#pragma unroll
    for (int j = 0; j < 8; j++) {
        int col = j * 16 + l16;
#pragma unroll
        for (int r = 0; r < 4; r++) {
            int gr = rowb + r;
            if (gr >= N) continue;
            acc2[j][r] += bv[j] + x[(size_t)gr * D + col];
        }
    }
    if (!DOLN) {
#pragma unroll
        for (int j = 0; j < 8; j++) {
            int col = j * 16 + l16;
#pragma unroll
            for (int r = 0; r < 4; r++) {
                int gr = rowb + r;
                if (gr < N) x[(size_t)gr * D + col] = acc2[j][r];
            }
        }
        return;
    }
    float lsv[8], lbv[8];
#pragma unroll
    for (int j = 0; j < 8; j++) {
        lsv[j] = lns[j * 16 + l16];
        lbv[j] = lnb[j * 16 + l16];
    }
#pragma unroll
    for (int r = 0; r < 4; r++) {
        float s1 = 0.f, s2 = 0.f;
#pragma unroll
        for (int j = 0; j < 8; j++) {
            float v = acc2[j][r];
            s1 += v; s2 += v * v;
        }
        s1 += __shfl_xor(s1, 1, 64);  s2 += __shfl_xor(s2, 1, 64);
        s1 += __shfl_xor(s1, 2, 64);  s2 += __shfl_xor(s2, 2, 64);
        s1 += __shfl_xor(s1, 4, 64);  s2 += __shfl_xor(s2, 4, 64);
        s1 += __shfl_xor(s1, 8, 64);  s2 += __shfl_xor(s2, 8, 64);
        float mu = s1 * (1.f / 128.f);
        float var = s2 * (1.f / 128.f) - mu * mu;
        float rinv = rsqrtf(fmaxf(var, 0.f) + 1e-5f);
        int gr = rowb + r;
        if (gr >= N) continue;
#pragma unroll
        for (int j = 0; j < 8; j++) {
            int col = j * 16 + l16;
            float v = acc2[j][r];
            x[(size_t)gr * D + col] = v;
            outB[(size_t)gr * D + col] = __float2bfloat16((v - mu) * rinv * lsv[j] + lbv[j]);
        }
    }
}

// ---------------- encoder stage 1: hb = bf16(relu(f@w1+b1)) ----------------
__global__ void k_enc1(const float* __restrict__ feat,
                       const float* __restrict__ w1, const float* __restrict__ b1,
                       bf16* __restrict__ hb, int N) {
    __shared__ float fsh[TN][DIN];
    int n0 = blockIdx.x * TN;
    int j = threadIdx.x;            // 0..127
    int nvalid = min(TN, N - n0);
    for (int idx = j; idx < TN * DIN; idx += 128) {
        int n = idx / DIN, i = idx % DIN;
        fsh[n][i] = (n < nvalid) ? feat[(n0 + n) * DIN + i] : 0.f;
    }
    __syncthreads();
    float bb = b1[j];
#pragma unroll
    for (int n = 0; n < TN; n++) {
        float a = bb;
#pragma unroll
        for (int i = 0; i < DIN; i++) a += fsh[n][i] * w1[i * D + j];
        if (n < nvalid) hb[(size_t)(n0 + n) * D + j] = __float2bfloat16(fmaxf(a, 0.f));
    }
}

// ---------------- fused per-receiver softmax attention (8-lane edge-head) ----
__global__ __launch_bounds__(128) void k_attn(
        const bf16* __restrict__ qb, const uint* __restrict__ kvb,
        const int* __restrict__ deg, const int* __restrict__ eid,
        bf16* __restrict__ out, int N) {
    __shared__ float sl[32], sa[32][4];
    int r = blockIdx.x;
    int t = threadIdx.x;
    int wave = t >> 6, lane = t & 63;
    int g = lane & 7;                    // dim group
    int h = (lane >> 3) & 3;             // head
    int slot = wave * 2 + (lane >> 5);   // edge slot 0..3
    int d0 = h * 32 + g * 4;
    uint2 qw = *(const uint2*)(qb + (size_t)r * D + d0);
    float4 qv;
    qv.x = __uint_as_float(qw.x << 16);
    qv.y = __uint_as_float(qw.x & 0xFFFF0000u);
    qv.z = __uint_as_float(qw.y << 16);
    qv.w = __uint_as_float(qw.y & 0xFFFF0000u);
    int cnt = min(deg[r], MAXDEG);
    const int* row = eid + (size_t)r * MAXDEG;
    float l = 0.f, a0 = 0.f, a1 = 0.f, a2 = 0.f, a3 = 0.f;
    for (int base = 0; base < cnt; base += 8) {
        int eiA = base + slot, eiB = base + 4 + slot;
        bool vA = eiA < cnt, vB = eiB < cnt;
        int sA = vA ? row[eiA] : 0;
        int sB = vB ? row[eiB] : 0;
        uint4 wA = *(const uint4*)(kvb + (size_t)sA * D + d0);
        uint4 wB = *(const uint4*)(kvb + (size_t)sB * D + d0);
        {
            float k0 = __uint_as_float(wA.x << 16), v0 = __uint_as_float(wA.x & 0xFFFF0000u);
            float k1 = __uint_as_float(wA.y << 16), v1 = __uint_as_float(wA.y & 0xFFFF0000u);
            float k2 = __uint_as_float(wA.z << 16), v2 = __uint_as_float(wA.z & 0xFFFF0000u);
            float k3 = __uint_as_float(wA.w << 16), v3 = __uint_as_float(wA.w & 0xFFFF0000u);
            float p = qv.x * k0 + qv.y * k1 + qv.z * k2 + qv.w * k3;
            p += __shfl_xor(p, 1, 64);
            p += __shfl_xor(p, 2, 64);
            p += __shfl_xor(p, 4, 64);
            float e = vA ? exp2f(p) : 0.f;
            l += e;
            a0 += e * v0; a1 += e * v1; a2 += e * v2; a3 += e * v3;
        }
        {
            float k0 = __uint_as_float(wB.x << 16), v0 = __uint_as_float(wB.x & 0xFFFF0000u);
            float k1 = __uint_as_float(wB.y << 16), v1 = __uint_as_float(wB.y & 0xFFFF0000u);
            float k2 = __uint_as_float(wB.z << 16), v2 = __uint_as_float(wB.z & 0xFFFF0000u);
            float k3 = __uint_as_float(wB.w << 16), v3 = __uint_as_float(wB.w & 0xFFFF0000u);
            float p = qv.x * k0 + qv.y * k1 + qv.z * k2 + qv.w * k3;
            p += __shfl_xor(p, 1, 64);
            p += __shfl_xor(p, 2, 64);
            p += __shfl_xor(p, 4, 64);
            float e = vB ? exp2f(p) : 0.f;
            l += e;
            a0 += e * v0; a1 += e * v1; a2 += e * v2; a3 += e * v3;
        }
    }
    l  += __shfl_xor(l, 32, 64);
    a0 += __shfl_xor(a0, 32, 64);
    a1 += __shfl_xor(a1, 32, 64);
    a2 += __shfl_xor(a2, 32, 64);
    a3 += __shfl_xor(a3, 32, 64);
    if (wave == 1 && lane < 32) {
        sl[lane] = l;
        sa[lane][0] = a0; sa[lane][1] = a1; sa[lane][2] = a2; sa[lane][3] = a3;
    }
    __syncthreads();
    if (wave == 0 && lane < 32) {
        l += sl[lane];
        float inv = 1.f / (l + 1e-9f);
        bf16 o[4];
        o[0] = __float2bfloat16((a0 + sa[lane][0]) * inv);
        o[1] = __float2bfloat16((a1 + sa[lane][1]) * inv);
        o[2] = __float2bfloat16((a2 + sa[lane][2]) * inv);
        o[3] = __float2bfloat16((a3 + sa[lane][3]) * inv);
        *(uint2*)(out + (size_t)r * D + d0) = *(uint2*)o;
    }
}

// ---------------- decoder: out = relu(x@w1+b1)@w2+b2, wave per node ----------
__global__ void k_decode(const float* __restrict__ x,
                         const float* __restrict__ w1, const float* __restrict__ b1,
                         const float* __restrict__ w2, const float* __restrict__ b2,
                         float* __restrict__ out, int N) {
    int node = blockIdx.x * 4 + (threadIdx.x >> 6);
    int lane = threadIdx.x & 63;
    if (node >= N) return;
    float a0 = x[(size_t)node * D + lane], a1 = x[(size_t)node * D + lane + 64];
    float acc0 = a0 * w1[lane * 3 + 0] + a1 * w1[(lane + 64) * 3 + 0];
    float acc1 = a0 * w1[lane * 3 + 1] + a1 * w1[(lane + 64) * 3 + 1];
    float acc2 = a0 * w1[lane * 3 + 2] + a1 * w1[(lane + 64) * 3 + 2];
#pragma unroll
    for (int m = 32; m >= 1; m >>= 1) {
        acc0 += __shfl_xor(acc0, m, 64);
        acc1 += __shfl_xor(acc1, m, 64);
        acc2 += __shfl_xor(acc2, m, 64);
    }
    if (lane == 0) {
        float t0 = fmaxf(acc0 + b1[0], 0.f);
        float t1 = fmaxf(acc1 + b1[1], 0.f);
        float t2 = fmaxf(acc2 + b1[2], 0.f);
        for (int o = 0; o < 3; o++)
            out[(size_t)node * 3 + o] =
                t0 * w2[0 * 3 + o] + t1 * w2[1 * 3 + o] + t2 * w2[2 * 3 + o] + b2[o];
    }
}

extern "C" void kernel_launch(void* const* d_in, const int* in_sizes, int n_in,
                              void* d_out, int out_size, void* d_ws, size_t ws_size,
                              hipStream_t stream) {
    const float* feat    = (const float*)d_in[0];
    const int*   senders = (const int*)d_in[1];
    const int*   recv    = (const int*)d_in[2];
    const float* enc_w1  = (const float*)d_in[3];
    const float* enc_b1  = (const float*)d_in[4];
    const float* enc_w2  = (const float*)d_in[5];
    const float* enc_b2  = (const float*)d_in[6];
    const float* wq      = (const float*)d_in[7];
    const float* wk      = (const float*)d_in[8];
    const float* wv      = (const float*)d_in[9];
    const float* wo      = (const float*)d_in[10];
    const float* ln1_s   = (const float*)d_in[11];
    const float* ln1_b   = (const float*)d_in[12];
    const float* ffn_w1  = (const float*)d_in[13];
    const float* ffn_b1  = (const float*)d_in[14];
    const float* ffn_w2  = (const float*)d_in[15];
    const float* ffn_b2  = (const float*)d_in[16];
    const float* ln2_s   = (const float*)d_in[17];
    const float* ln2_b   = (const float*)d_in[18];
    const float* dec_w1  = (const float*)d_in[19];
    const float* dec_b1  = (const float*)d_in[20];
    const float* dec_w2  = (const float*)d_in[21];
    const float* dec_b2  = (const float*)d_in[22];

    int N = in_sizes[0] / DIN;
    int E = in_sizes[1];

    // workspace layout
    char* p = (char*)d_ws;
    float* x   = (float*)p;  p += (size_t)N * D * 4;        // residual fp32
    bf16*  qb  = (bf16*)p;   p += (size_t)N * D * 2;        // q bf16 (pre-scaled)
    bf16*  kvb = (bf16*)p;   p += (size_t)N * D * 2 * 2;    // (k,v) bf16 interleaved
    bf16*  hb  = (bf16*)p;   p += (size_t)N * D * 2;        // LN out / attn out bf16
    int* deg   = (int*)p;    p += (size_t)N * 4;
    int* eid   = (int*)p;    p += (size_t)N * MAXDEG * 4;
    bf16* wqkvT  = (bf16*)p; p += (size_t)4 * 3 * D * D * 2;
    bf16* woT    = (bf16*)p; p += (size_t)4 * D * D * 2;
    bf16* w1T    = (bf16*)p; p += (size_t)4 * D * DFF * 2;
    bf16* w2T    = (bf16*)p; p += (size_t)4 * DFF * D * 2;
    bf16* encw2T = (bf16*)p; p += (size_t)D * D * 2;

    int gm = (N + BM - 1) / BM;   // 782

    k_wt<<<dim3(256, 25), 256, 0, stream>>>(wq, wk, wv, wo, ffn_w1, ffn_w2, enc_w2,
                                            wqkvT, woT, w1T, w2T, encw2T);
    k_zero_int<<<(N + 255) / 256, 256, 0, stream>>>(deg, N);
    k_fill<<<(E + 255) / 256, 256, 0, stream>>>(recv, senders, deg, eid, E);
    k_enc1<<<(N + TN - 1) / TN, 128, 0, stream>>>(feat, enc_w1, enc_b1, hb, N);
    // x = hb @ enc_w2 + b2; hb = LN1_0(x)
    k_gemm<5><<<gm, 256, 0, stream>>>(hb, encw2T, enc_b2, ln1_s, ln1_b, x, hb, N);

    for (int l = 0; l < 4; l++) {
        k_qkv<<<gm, 256, 0, stream>>>(hb, wqkvT + (size_t)l * 3 * D * D, qb, kvb, N);
        k_attn<<<N, 128, 0, stream>>>(qb, (const uint*)kvb, deg, eid, hb, N);
        // x += hb @ wo; hb = LN2(x)
        k_gemm<2><<<gm, 256, 0, stream>>>(hb, woT + (size_t)l * D * D,
                                          nullptr, ln2_s + l * D, ln2_b + l * D,
                                          x, hb, N);
        // x += relu(hb@w1+b1)@w2 + b2; [LN1_{l+1} -> hb]
        if (l < 3)
            k_ffn<true><<<gm, 256, 0, stream>>>(hb, w1T + (size_t)l * D * DFF,
                                                ffn_b1 + l * DFF,
                                                w2T + (size_t)l * DFF * D, ffn_b2 + l * D,
                                                ln1_s + (l + 1) * D, ln1_b + (l + 1) * D,
                                                x, hb, N);
        else
            k_ffn<false><<<gm, 256, 0, stream>>>(hb, w1T + (size_t)l * D * DFF,
                                                 ffn_b1 + l * DFF,
                                                 w2T + (size_t)l * DFF * D, ffn_b2 + l * D,
                                                 nullptr, nullptr, x, nullptr, N);
    }
    k_decode<<<(N + 3) / 4, 256, 0, stream>>>(x, dec_w1, dec_b1, dec_w2, dec_b2,
                                              (float*)d_out, N);
}